// Round 1
// baseline (1045.790 us; speedup 1.0000x reference)
//
#include <hip/hip_runtime.h>
#include <stdint.h>

#define NB 8
#define NC 256
#define NPIX 16384

typedef float f32x4 __attribute__((ext_vector_type(4)));
typedef short short8 __attribute__((ext_vector_type(8)));

// workspace layout in floats
#define WS_G     0          // 8*256*256
#define WS_S     524288     // 8*256
#define WS_PQ    526336     // 8*256*256
#define WS_U     1050624    // 8*256
#define WS_W     1052672    // 8*256
#define WS_WKT   1054720    // 256*256
#define WS_MGT   1120256    // 8*256*256
#define WS_TV    1644544    // 8*256
// total 1646592 floats = 6.6 MB

__device__ __forceinline__ void splitbf(float f, unsigned short& h, unsigned short& l) {
    __bf16 hb = (__bf16)f;
    float r = f - (float)hb;
    __bf16 lb = (__bf16)r;
    h = __builtin_bit_cast(unsigned short, hb);
    l = __builtin_bit_cast(unsigned short, lb);
}

// ---------------- misc: transpose Wk, zero S ----------------
__global__ void k_misc(const float* __restrict__ Wk, float* __restrict__ WkT,
                       float* __restrict__ S) {
    int c = blockIdx.x, t = threadIdx.x;
    WkT[c * 256 + t] = Wk[t * 256 + c];
    if (c < 8) S[c * 256 + t] = 0.f;
}

// ---------------- Gram: per (b, chunk) partial G = X X^T, 256x256 tile ----------------
// hi/lo bf16 split, 3 MFMA passes -> ~fp32 precision. Also accumulates row sums into S.
__global__ __launch_bounds__(512, 2) void k_gemmA(const float* __restrict__ X,
                                                  float* __restrict__ Pout,
                                                  float* __restrict__ S) {
    int bx = blockIdx.x;            // 256 blocks = 8 b * 32 chunks
    int b = bx >> 5, ch = bx & 31;  // chunk = 512 pixels
    int tid = threadIdx.x;
    int lane = tid & 63;
    int w = tid >> 6;               // 8 waves: 2 x 4
    int wrow = w >> 2, wcol = w & 3;
    int lrow = lane & 15;
    int lk8 = (lane >> 4) << 3;

    __shared__ __align__(16) unsigned short Thi[256 * 64];
    __shared__ __align__(16) unsigned short Tlo[256 * 64];

    f32x4 zero4 = {0.f, 0.f, 0.f, 0.f};
    f32x4 acc[8][4];
#pragma unroll
    for (int mi = 0; mi < 8; ++mi)
#pragma unroll
        for (int ni = 0; ni < 4; ++ni) acc[mi][ni] = zero4;

    float rsum[8];
#pragma unroll
    for (int i = 0; i < 8; ++i) rsum[i] = 0.f;

    const float* Xb = X + (size_t)b * NC * NPIX + ch * 512;

    for (int kk = 0; kk < 8; ++kk) {   // 8 * BK64 = 512 pixels
        __syncthreads();
        // stage 256 rows x 64 cols fp32 -> hi/lo bf16 LDS (XOR swizzled)
#pragma unroll
        for (int i = 0; i < 8; ++i) {
            int flat = tid + i * 512;       // 0..4095 float4
            int r = flat >> 4;
            int k4 = flat & 15;
            float4 v = *(const float4*)(Xb + (size_t)r * NPIX + kk * 64 + k4 * 4);
            rsum[i] += v.x + v.y + v.z + v.w;
            unsigned short h0, h1, h2, h3, l0, l1, l2, l3;
            splitbf(v.x, h0, l0); splitbf(v.y, h1, l1);
            splitbf(v.z, h2, l2); splitbf(v.w, h3, l3);
            int e0 = (r * 64 + k4 * 4) ^ ((r & 7) << 3);
            uint2 hu, lu;
            hu.x = (unsigned)h0 | ((unsigned)h1 << 16);
            hu.y = (unsigned)h2 | ((unsigned)h3 << 16);
            lu.x = (unsigned)l0 | ((unsigned)l1 << 16);
            lu.y = (unsigned)l2 | ((unsigned)l3 << 16);
            *(uint2*)&Thi[e0] = hu;
            *(uint2*)&Tlo[e0] = lu;
        }
        __syncthreads();
#pragma unroll
        for (int ks = 0; ks < 2; ++ks) {
            short8 bh[4], bl[4];
#pragma unroll
            for (int ni = 0; ni < 4; ++ni) {
                int row = wcol * 64 + ni * 16 + lrow;
                int e = (row * 64 + ks * 32 + lk8) ^ ((row & 7) << 3);
                bh[ni] = *(const short8*)&Thi[e];
                bl[ni] = *(const short8*)&Tlo[e];
            }
#pragma unroll
            for (int mi = 0; mi < 8; ++mi) {
                int row = wrow * 128 + mi * 16 + lrow;
                int e = (row * 64 + ks * 32 + lk8) ^ ((row & 7) << 3);
                short8 ah = *(const short8*)&Thi[e];
                short8 al = *(const short8*)&Tlo[e];
#pragma unroll
                for (int ni = 0; ni < 4; ++ni) {
                    acc[mi][ni] = __builtin_amdgcn_mfma_f32_16x16x32_bf16(ah, bh[ni], acc[mi][ni], 0, 0, 0);
                    acc[mi][ni] = __builtin_amdgcn_mfma_f32_16x16x32_bf16(ah, bl[ni], acc[mi][ni], 0, 0, 0);
                    acc[mi][ni] = __builtin_amdgcn_mfma_f32_16x16x32_bf16(al, bh[ni], acc[mi][ni], 0, 0, 0);
                }
            }
        }
    }
    // partial store (layout = final G layout, per (b,chunk) slot)
    float* pb = Pout + ((size_t)(b * 32 + ch)) * 65536;
    int lr4 = (lane >> 4) << 2;
    int lc = lane & 15;
#pragma unroll
    for (int mi = 0; mi < 8; ++mi)
#pragma unroll
        for (int ni = 0; ni < 4; ++ni)
#pragma unroll
            for (int j = 0; j < 4; ++j) {
                int gr = wrow * 128 + mi * 16 + lr4 + j;
                int gc = wcol * 64 + ni * 16 + lc;
                pb[gr * 256 + gc] = acc[mi][ni][j];
            }
#pragma unroll
    for (int i = 0; i < 8; ++i)
        atomicAdd(&S[b * 256 + (tid >> 4) + 32 * i], rsum[i]);
}

// ---------------- reduce 32 chunk-partials -> G ----------------
__global__ void k_reduce(const float* __restrict__ Pin, float* __restrict__ G) {
    int bx = blockIdx.x;            // 256 = 8 b * 32 segs
    int b = bx >> 5, seg = bx & 31;
    int t = threadIdx.x;
#pragma unroll
    for (int k = 0; k < 8; ++k) {
        int i = seg * 2048 + k * 256 + t;
        float s = 0.f;
        for (int chk = 0; chk < 32; ++chk)
            s += Pin[((size_t)(b * 32 + chk)) * 65536 + i];
        G[(size_t)b * 65536 + i] = s;
    }
}

// ---------------- B1: Pq = Wq * G_b ----------------
__global__ __launch_bounds__(256) void k_B1(const float* __restrict__ Wq,
                                            const float* __restrict__ G,
                                            float* __restrict__ Pq) {
    int bx = blockIdx.x;            // 128 = 8 b * 4 rowtiles * 4 coltiles
    int b = bx >> 4, rt = (bx >> 2) & 3, ct = bx & 3;
    int t = threadIdx.x;
    __shared__ float WqLds[64 * 257];
    int rbase = rt * 64;
#pragma unroll
    for (int i = 0; i < 16; ++i) {
        int flat = t + i * 256;
        int di = flat >> 6;
        int c4 = (flat & 63) * 4;
        float4 v = *(const float4*)(Wq + (size_t)(rbase + di) * 256 + c4);
        WqLds[di * 257 + c4 + 0] = v.x;
        WqLds[di * 257 + c4 + 1] = v.y;
        WqLds[di * 257 + c4 + 2] = v.z;
        WqLds[di * 257 + c4 + 3] = v.w;
    }
    __syncthreads();
    int di = t & 63, cg = t >> 6;
    int colbase = ct * 64 + cg * 16;
    float acc[16];
#pragma unroll
    for (int j = 0; j < 16; ++j) acc[j] = 0.f;
    const float* Gb = G + (size_t)b * 65536;
    for (int c = 0; c < 256; ++c) {
        float wq = WqLds[di * 257 + c];
        const float* gr = Gb + c * 256 + colbase;
#pragma unroll
        for (int j = 0; j < 16; ++j) acc[j] += wq * gr[j];
    }
    float* outp = Pq + ((size_t)(b * 256 + rbase + di)) * 256 + colbase;
#pragma unroll
    for (int j = 0; j < 16; ++j) outp[j] = acc[j];
}

// ---------------- uw: u = Wq s, w = Wk s ----------------
__global__ void k_uw(const float* __restrict__ Wq, const float* __restrict__ Wk,
                     const float* __restrict__ S, float* __restrict__ U,
                     float* __restrict__ Wvec) {
    int b = blockIdx.x, d = threadIdx.x;
    float u = 0.f, w = 0.f;
    for (int c = 0; c < 256; ++c) {
        float sv = S[b * 256 + c];
        u += Wq[(size_t)d * 256 + c] * sv;
        w += Wk[(size_t)d * 256 + c] * sv;
    }
    U[b * 256 + d] = u;
    Wvec[b * 256 + d] = w;
}

// ---------------- B2: logits -> softmax -> MgT = gamma*(attn Wv)^T, Tvec ----------------
__global__ __launch_bounds__(256) void k_B2(const float* __restrict__ Pq,
                                            const float* __restrict__ WkT,
                                            const float* __restrict__ bq,
                                            const float* __restrict__ bk,
                                            const float* __restrict__ bv,
                                            const float* __restrict__ Wv,
                                            const float* __restrict__ U,
                                            const float* __restrict__ Wvec,
                                            const float* __restrict__ gamma,
                                            float* __restrict__ MgT,
                                            float* __restrict__ Tvec) {
    int bx = blockIdx.x;            // 32 = 8 b * 2 h * 2 rowtiles
    int b = bx >> 2, h = (bx >> 1) & 1, rt = bx & 1;
    int t = threadIdx.x;
    __shared__ float PqLds[64 * 257];
    __shared__ float P[64 * 129];
    int Dbase = h * 128 + rt * 64;
#pragma unroll
    for (int i = 0; i < 16; ++i) {
        int flat = t + i * 256;
        int di = flat >> 6;
        int c4 = (flat & 63) * 4;
        float4 v = *(const float4*)(Pq + ((size_t)(b * 256 + Dbase + di)) * 256 + c4);
        PqLds[di * 257 + c4 + 0] = v.x;
        PqLds[di * 257 + c4 + 1] = v.y;
        PqLds[di * 257 + c4 + 2] = v.z;
        PqLds[di * 257 + c4 + 3] = v.w;
    }
    __syncthreads();
    int di = t & 63, eg = t >> 6;
    int Eb = h * 128 + eg * 32;
    {
        float acc[32];
#pragma unroll
        for (int j = 0; j < 32; ++j) acc[j] = 0.f;
        for (int c = 0; c < 256; ++c) {
            float p = PqLds[di * 257 + c];
            const float* kr = WkT + c * 256 + Eb;
#pragma unroll
            for (int ej = 0; ej < 32; ++ej) acc[ej] += p * kr[ej];
        }
        int D = Dbase + di;
        float bqD = bq[D], uD = U[b * 256 + D];
#pragma unroll
        for (int ej = 0; ej < 32; ++ej) {
            int E = Eb + ej;
            float l = acc[ej] + bqD * Wvec[b * 256 + E] + bk[E] * uD + 16384.f * bqD * bk[E];
            P[di * 129 + eg * 32 + ej] = l;
        }
    }
    __syncthreads();
    if (t < 64) {
        float m = -3.0e38f;
        for (int j = 0; j < 128; ++j) m = fmaxf(m, P[t * 129 + j]);
        float ss = 0.f;
        for (int j = 0; j < 128; ++j) {
            float e = __expf(P[t * 129 + j] - m);
            P[t * 129 + j] = e;
            ss += e;
        }
        float inv = 1.f / ss;
        for (int j = 0; j < 128; ++j) P[t * 129 + j] *= inv;
    }
    __syncthreads();
    float g0 = gamma[0];
    {
        int cb = (t >> 6) * 64;
        float acc2[64];
#pragma unroll
        for (int j = 0; j < 64; ++j) acc2[j] = 0.f;
        for (int ej = 0; ej < 128; ++ej) {
            float p = P[di * 129 + ej];
            const float* wr = Wv + (size_t)(h * 128 + ej) * 256 + cb;
#pragma unroll
            for (int cj = 0; cj < 64; ++cj) acc2[cj] += p * wr[cj];
        }
        int Dfull = Dbase + di;
#pragma unroll
        for (int cj = 0; cj < 64; ++cj)
            MgT[((size_t)(b * 256 + cb + cj)) * 256 + Dfull] = g0 * acc2[cj];
    }
    if (t < 64) {
        float tv = 0.f;
        for (int j = 0; j < 128; ++j) tv += P[t * 129 + j] * bv[h * 128 + j];
        Tvec[b * 256 + Dbase + t] = g0 * tv;
    }
}

// ---------------- apply: Y = MgT^T X + Tvec + X ----------------
__global__ __launch_bounds__(256, 2) void k_gemmC(const float* __restrict__ X,
                                                  const float* __restrict__ MgT,
                                                  const float* __restrict__ Tvec,
                                                  float* __restrict__ Y) {
    int bx = blockIdx.x;            // 1024, XCD-grouped so rt pairs share an XCD L2
    int x = bx & 7;
    int k = bx >> 3;
    int gid = ((k >> 1) << 3) | x;
    int rt = k & 1;
    int b = gid >> 6, nt = gid & 63;
    int t = threadIdx.x;
    int n = nt * 256 + t;
    int r0 = rt * 128;
    float acc[128];
#pragma unroll
    for (int r = 0; r < 128; ++r) acc[r] = 0.f;
    const float* Xb = X + (size_t)b * NC * NPIX;
    for (int c = 0; c < 256; ++c) {
        float xv = Xb[(size_t)c * NPIX + n];
        const float* mr = MgT + ((size_t)(b * 256 + c)) * 256 + r0;
#pragma unroll
        for (int r = 0; r < 128; ++r) acc[r] += mr[r] * xv;
    }
#pragma unroll
    for (int r = 0; r < 128; ++r) {
        size_t o = ((size_t)(b * 256 + r0 + r)) * NPIX + n;
        Y[o] = acc[r] + Tvec[b * 256 + r0 + r] + Xb[(size_t)(r0 + r) * NPIX + n];
    }
}

extern "C" void kernel_launch(void* const* d_in, const int* in_sizes, int n_in,
                              void* d_out, int out_size, void* d_ws, size_t ws_size,
                              hipStream_t stream) {
    (void)in_sizes; (void)n_in; (void)out_size; (void)ws_size;
    const float* X     = (const float*)d_in[0];
    const float* Wq    = (const float*)d_in[1];
    const float* bq    = (const float*)d_in[2];
    const float* Wk    = (const float*)d_in[3];
    const float* bk    = (const float*)d_in[4];
    const float* Wv    = (const float*)d_in[5];
    const float* bv    = (const float*)d_in[6];
    const float* gamma = (const float*)d_in[7];
    float* Y  = (float*)d_out;
    float* ws = (float*)d_ws;

    float* G    = ws + WS_G;
    float* S    = ws + WS_S;
    float* Pq   = ws + WS_PQ;
    float* U    = ws + WS_U;
    float* Wvec = ws + WS_W;
    float* WkT  = ws + WS_WKT;
    float* MgT  = ws + WS_MGT;
    float* Tvec = ws + WS_TV;
    float* Part = Y;   // reuse 134MB output buffer as 64MB Gram-partial scratch
                       // (consumed by k_reduce before k_gemmC overwrites it)

    k_misc<<<dim3(256), dim3(256), 0, stream>>>(Wk, WkT, S);
    k_gemmA<<<dim3(256), dim3(512), 0, stream>>>(X, Part, S);
    k_reduce<<<dim3(256), dim3(256), 0, stream>>>(Part, G);
    k_B1<<<dim3(128), dim3(256), 0, stream>>>(Wq, G, Pq);
    k_uw<<<dim3(8), dim3(256), 0, stream>>>(Wq, Wk, S, U, Wvec);
    k_B2<<<dim3(32), dim3(256), 0, stream>>>(Pq, WkT, bq, bk, bv, Wv, U, Wvec, gamma, MgT, Tvec);
    k_gemmC<<<dim3(1024), dim3(256), 0, stream>>>(X, MgT, Tvec, Y);
}

// Round 2
// 578.792 us; speedup vs baseline: 1.8068x; 1.8068x over previous
//
#include <hip/hip_runtime.h>
#include <stdint.h>

#define NB 8
#define NC 256
#define NPIX 16384

typedef float f32x4 __attribute__((ext_vector_type(4)));
typedef short short8 __attribute__((ext_vector_type(8)));

// workspace layout in floats
#define WS_G     0          // 8*256*256
#define WS_S     524288     // 8*256
#define WS_PQ    526336     // 8*256*256
#define WS_U     1050624    // 8*256
#define WS_W     1052672    // 8*256
#define WS_WKT   1054720    // 256*256
#define WS_WQT   1120256    // 256*256
#define WS_MGBF  1185792    // 8*256*256 bf16 = 262144 floats
#define WS_TV    1447936    // 8*256
// total 1449984 floats = 5.8 MB

__device__ __forceinline__ void splitbf(float f, unsigned short& h, unsigned short& l) {
    __bf16 hb = (__bf16)f;
    float r = f - (float)hb;
    __bf16 lb = (__bf16)r;
    h = __builtin_bit_cast(unsigned short, hb);
    l = __builtin_bit_cast(unsigned short, lb);
}

__device__ __forceinline__ unsigned short bf16bits(float f) {
    return __builtin_bit_cast(unsigned short, (__bf16)f);
}

// ---------------- misc: transpose Wq & Wk, zero S ----------------
__global__ void k_misc(const float* __restrict__ Wq, const float* __restrict__ Wk,
                       float* __restrict__ WqT, float* __restrict__ WkT,
                       float* __restrict__ S) {
    int c = blockIdx.x, t = threadIdx.x;
    WqT[c * 256 + t] = Wq[t * 256 + c];
    WkT[c * 256 + t] = Wk[t * 256 + c];
    if (c < 8) S[c * 256 + t] = 0.f;
}

// ---------------- Gram: per (b, chunk) partial G = X X^T, 256x256 tile ----------------
// hi/lo bf16 split, 3 MFMA passes -> ~fp32 precision. Also accumulates row sums into S.
__global__ __launch_bounds__(512, 2) void k_gemmA(const float* __restrict__ X,
                                                  float* __restrict__ Pout,
                                                  float* __restrict__ S) {
    int bx = blockIdx.x;            // 256 blocks = 8 b * 32 chunks
    int b = bx >> 5, ch = bx & 31;  // chunk = 512 pixels
    int tid = threadIdx.x;
    int lane = tid & 63;
    int w = tid >> 6;               // 8 waves: 2 x 4
    int wrow = w >> 2, wcol = w & 3;
    int lrow = lane & 15;
    int lk8 = (lane >> 4) << 3;

    __shared__ __align__(16) unsigned short Thi[256 * 64];
    __shared__ __align__(16) unsigned short Tlo[256 * 64];

    f32x4 zero4 = {0.f, 0.f, 0.f, 0.f};
    f32x4 acc[8][4];
#pragma unroll
    for (int mi = 0; mi < 8; ++mi)
#pragma unroll
        for (int ni = 0; ni < 4; ++ni) acc[mi][ni] = zero4;

    float rsum[8];
#pragma unroll
    for (int i = 0; i < 8; ++i) rsum[i] = 0.f;

    const float* Xb = X + (size_t)b * NC * NPIX + ch * 512;

    for (int kk = 0; kk < 8; ++kk) {   // 8 * BK64 = 512 pixels
        __syncthreads();
        // stage 256 rows x 64 cols fp32 -> hi/lo bf16 LDS (XOR swizzled)
#pragma unroll
        for (int i = 0; i < 8; ++i) {
            int flat = tid + i * 512;       // 0..4095 float4
            int r = flat >> 4;
            int k4 = flat & 15;
            float4 v = *(const float4*)(Xb + (size_t)r * NPIX + kk * 64 + k4 * 4);
            rsum[i] += v.x + v.y + v.z + v.w;
            unsigned short h0, h1, h2, h3, l0, l1, l2, l3;
            splitbf(v.x, h0, l0); splitbf(v.y, h1, l1);
            splitbf(v.z, h2, l2); splitbf(v.w, h3, l3);
            int e0 = (r * 64 + k4 * 4) ^ ((r & 7) << 3);
            uint2 hu, lu;
            hu.x = (unsigned)h0 | ((unsigned)h1 << 16);
            hu.y = (unsigned)h2 | ((unsigned)h3 << 16);
            lu.x = (unsigned)l0 | ((unsigned)l1 << 16);
            lu.y = (unsigned)l2 | ((unsigned)l3 << 16);
            *(uint2*)&Thi[e0] = hu;
            *(uint2*)&Tlo[e0] = lu;
        }
        __syncthreads();
#pragma unroll
        for (int ks = 0; ks < 2; ++ks) {
            short8 bh[4], bl[4];
#pragma unroll
            for (int ni = 0; ni < 4; ++ni) {
                int row = wcol * 64 + ni * 16 + lrow;
                int e = (row * 64 + ks * 32 + lk8) ^ ((row & 7) << 3);
                bh[ni] = *(const short8*)&Thi[e];
                bl[ni] = *(const short8*)&Tlo[e];
            }
#pragma unroll
            for (int mi = 0; mi < 8; ++mi) {
                int row = wrow * 128 + mi * 16 + lrow;
                int e = (row * 64 + ks * 32 + lk8) ^ ((row & 7) << 3);
                short8 ah = *(const short8*)&Thi[e];
                short8 al = *(const short8*)&Tlo[e];
#pragma unroll
                for (int ni = 0; ni < 4; ++ni) {
                    acc[mi][ni] = __builtin_amdgcn_mfma_f32_16x16x32_bf16(ah, bh[ni], acc[mi][ni], 0, 0, 0);
                    acc[mi][ni] = __builtin_amdgcn_mfma_f32_16x16x32_bf16(ah, bl[ni], acc[mi][ni], 0, 0, 0);
                    acc[mi][ni] = __builtin_amdgcn_mfma_f32_16x16x32_bf16(al, bh[ni], acc[mi][ni], 0, 0, 0);
                }
            }
        }
    }
    // partial store (layout = final G layout, per (b,chunk) slot)
    float* pb = Pout + ((size_t)(b * 32 + ch)) * 65536;
    int lr4 = (lane >> 4) << 2;
    int lc = lane & 15;
#pragma unroll
    for (int mi = 0; mi < 8; ++mi)
#pragma unroll
        for (int ni = 0; ni < 4; ++ni)
#pragma unroll
            for (int j = 0; j < 4; ++j) {
                int gr = wrow * 128 + mi * 16 + lr4 + j;
                int gc = wcol * 64 + ni * 16 + lc;
                pb[gr * 256 + gc] = acc[mi][ni][j];
            }
    // row-sum reduce: 16 consecutive lanes share a row -> shuffle, 1 atomic per row
#pragma unroll
    for (int i = 0; i < 8; ++i) {
        float rs = rsum[i];
        rs += __shfl_down(rs, 8, 16);
        rs += __shfl_down(rs, 4, 16);
        rs += __shfl_down(rs, 2, 16);
        rs += __shfl_down(rs, 1, 16);
        if ((tid & 15) == 0)
            atomicAdd(&S[b * 256 + (tid >> 4) + 32 * i], rs);
    }
}

// ---------------- reduce 32 chunk-partials -> G ----------------
__global__ void k_reduce(const float* __restrict__ Pin, float* __restrict__ G) {
    int bx = blockIdx.x;            // 256 = 8 b * 32 segs
    int b = bx >> 5, seg = bx & 31;
    int t = threadIdx.x;
#pragma unroll
    for (int k = 0; k < 8; ++k) {
        int i = seg * 2048 + k * 256 + t;
        float s = 0.f;
        for (int chk = 0; chk < 32; ++chk)
            s += Pin[((size_t)(b * 32 + chk)) * 65536 + i];
        G[(size_t)b * 65536 + i] = s;
    }
}

// ---------------- B1: Pq = Wq * G_b ----------------
__global__ __launch_bounds__(256) void k_B1(const float* __restrict__ Wq,
                                            const float* __restrict__ G,
                                            float* __restrict__ Pq) {
    int bx = blockIdx.x;            // 128 = 8 b * 4 rowtiles * 4 coltiles
    int b = bx >> 4, rt = (bx >> 2) & 3, ct = bx & 3;
    int t = threadIdx.x;
    __shared__ float WqLds[64 * 257];
    int rbase = rt * 64;
#pragma unroll
    for (int i = 0; i < 16; ++i) {
        int flat = t + i * 256;
        int di = flat >> 6;
        int c4 = (flat & 63) * 4;
        float4 v = *(const float4*)(Wq + (size_t)(rbase + di) * 256 + c4);
        WqLds[di * 257 + c4 + 0] = v.x;
        WqLds[di * 257 + c4 + 1] = v.y;
        WqLds[di * 257 + c4 + 2] = v.z;
        WqLds[di * 257 + c4 + 3] = v.w;
    }
    __syncthreads();
    int di = t & 63, cg = t >> 6;
    int colbase = ct * 64 + cg * 16;
    float acc[16];
#pragma unroll
    for (int j = 0; j < 16; ++j) acc[j] = 0.f;
    const float* Gb = G + (size_t)b * 65536;
    for (int c = 0; c < 256; ++c) {
        float wq = WqLds[di * 257 + c];
        const float* gr = Gb + c * 256 + colbase;
#pragma unroll
        for (int j = 0; j < 16; ++j) acc[j] += wq * gr[j];
    }
    float* outp = Pq + ((size_t)(b * 256 + rbase + di)) * 256 + colbase;
#pragma unroll
    for (int j = 0; j < 16; ++j) outp[j] = acc[j];
}

// ---------------- uw: u = Wq s, w = Wk s (coalesced via transposed weights) ----------------
__global__ void k_uw(const float* __restrict__ WqT, const float* __restrict__ WkT,
                     const float* __restrict__ S, float* __restrict__ U,
                     float* __restrict__ Wvec) {
    int b = blockIdx.x, d = threadIdx.x;
    __shared__ float sl[256];
    sl[d] = S[b * 256 + d];
    __syncthreads();
    float u = 0.f, w = 0.f;
    for (int c = 0; c < 256; ++c) {
        float sv = sl[c];
        u += WqT[c * 256 + d] * sv;
        w += WkT[c * 256 + d] * sv;
    }
    U[b * 256 + d] = u;
    Wvec[b * 256 + d] = w;
}

// ---------------- B2: logits -> softmax -> Mg = gamma*attn*Wv (bf16, row-major), Tvec ----------------
__global__ __launch_bounds__(256) void k_B2(const float* __restrict__ Pq,
                                            const float* __restrict__ WkT,
                                            const float* __restrict__ bq,
                                            const float* __restrict__ bk,
                                            const float* __restrict__ bv,
                                            const float* __restrict__ Wv,
                                            const float* __restrict__ U,
                                            const float* __restrict__ Wvec,
                                            const float* __restrict__ gamma,
                                            unsigned short* __restrict__ Mgb,
                                            float* __restrict__ Tvec) {
    int bx = blockIdx.x;            // 32 = 8 b * 2 h * 2 rowtiles
    int b = bx >> 2, h = (bx >> 1) & 1, rt = bx & 1;
    int t = threadIdx.x;
    __shared__ float PqLds[64 * 257];
    __shared__ float P[64 * 129];
    int Dbase = h * 128 + rt * 64;
#pragma unroll
    for (int i = 0; i < 16; ++i) {
        int flat = t + i * 256;
        int di = flat >> 6;
        int c4 = (flat & 63) * 4;
        float4 v = *(const float4*)(Pq + ((size_t)(b * 256 + Dbase + di)) * 256 + c4);
        PqLds[di * 257 + c4 + 0] = v.x;
        PqLds[di * 257 + c4 + 1] = v.y;
        PqLds[di * 257 + c4 + 2] = v.z;
        PqLds[di * 257 + c4 + 3] = v.w;
    }
    __syncthreads();
    int di = t & 63, eg = t >> 6;
    int Eb = h * 128 + eg * 32;
    {
        float acc[32];
#pragma unroll
        for (int j = 0; j < 32; ++j) acc[j] = 0.f;
        for (int c = 0; c < 256; ++c) {
            float p = PqLds[di * 257 + c];
            const float* kr = WkT + c * 256 + Eb;
#pragma unroll
            for (int ej = 0; ej < 32; ++ej) acc[ej] += p * kr[ej];
        }
        int D = Dbase + di;
        float bqD = bq[D], uD = U[b * 256 + D];
#pragma unroll
        for (int ej = 0; ej < 32; ++ej) {
            int E = Eb + ej;
            float l = acc[ej] + bqD * Wvec[b * 256 + E] + bk[E] * uD + 16384.f * bqD * bk[E];
            P[di * 129 + eg * 32 + ej] = l;
        }
    }
    __syncthreads();
    // wave-parallel softmax: 4 threads per row (same wave), shfl_xor width-4 reduce
    {
        int row = t >> 2, sub = t & 3;
        float* Pr = &P[row * 129 + sub * 32];
        float m = -3.0e38f;
#pragma unroll
        for (int j = 0; j < 32; ++j) m = fmaxf(m, Pr[j]);
        m = fmaxf(m, __shfl_xor(m, 1, 4));
        m = fmaxf(m, __shfl_xor(m, 2, 4));
        float ss = 0.f;
#pragma unroll
        for (int j = 0; j < 32; ++j) {
            float e = __expf(Pr[j] - m);
            Pr[j] = e;
            ss += e;
        }
        ss += __shfl_xor(ss, 1, 4);
        ss += __shfl_xor(ss, 2, 4);
        float inv = 1.f / ss;
#pragma unroll
        for (int j = 0; j < 32; ++j) Pr[j] *= inv;
    }
    __syncthreads();
    float g0 = gamma[0];
    {
        int cb = (t >> 6) * 64;
        float acc2[64];
#pragma unroll
        for (int j = 0; j < 64; ++j) acc2[j] = 0.f;
        for (int ej = 0; ej < 128; ++ej) {
            float p = P[di * 129 + ej];
            const float* wr = Wv + (size_t)(h * 128 + ej) * 256 + cb;
#pragma unroll
            for (int cj = 0; cj < 64; ++cj) acc2[cj] += p * wr[cj];
        }
        // row-major bf16 Mg write, packed as uint
        unsigned int* Mp = (unsigned int*)(Mgb + ((size_t)(b * 256 + Dbase + di)) * 256 + cb);
#pragma unroll
        for (int cj = 0; cj < 64; cj += 2) {
            unsigned short a0 = bf16bits(g0 * acc2[cj]);
            unsigned short a1 = bf16bits(g0 * acc2[cj + 1]);
            Mp[cj >> 1] = (unsigned)a0 | ((unsigned)a1 << 16);
        }
    }
    if (t < 64) {
        float tv = 0.f;
        for (int j = 0; j < 128; ++j) tv += P[t * 129 + j] * bv[h * 128 + j];
        Tvec[b * 256 + Dbase + t] = g0 * tv;
    }
}

// ---------------- apply: Y = Mg X + Tvec + X  (bf16 MFMA, fp32 residual from LDS) ----------------
__global__ __launch_bounds__(256, 2) void k_gemmC(const float* __restrict__ X,
                                                  const unsigned short* __restrict__ Mgb,
                                                  const float* __restrict__ Tvec,
                                                  float* __restrict__ Y) {
    int bx = blockIdx.x;            // 2048 = 8 b * 256 ntiles of 64 px
    int b = bx >> 8, nt = bx & 255;
    int n0 = nt * 64;
    int tid = threadIdx.x;
    int lane = tid & 63, w = tid >> 6;   // 4 waves; wave w owns rows w*64..w*64+63

    __shared__ float XL[256 * 64];

    // stage X[0:256][n0:n0+64] fp32 -> LDS (coalesced float4, no conversion)
    const float* Xb = X + (size_t)b * NC * NPIX + n0;
#pragma unroll
    for (int i = 0; i < 16; ++i) {
        int flat = tid + i * 256;       // 0..4095 float4 slots
        int c = flat >> 4;
        int n4 = (flat & 15) * 4;
        *(float4*)&XL[c * 64 + n4] = *(const float4*)(Xb + (size_t)c * NPIX + n4);
    }
    __syncthreads();

    int lr = lane & 15;
    int lk = (lane >> 4) * 8;

    f32x4 zero4 = {0.f, 0.f, 0.f, 0.f};
    f32x4 acc[4][4];
#pragma unroll
    for (int mi = 0; mi < 4; ++mi)
#pragma unroll
        for (int ni = 0; ni < 4; ++ni) acc[mi][ni] = zero4;

    const unsigned short* Mb = Mgb + (size_t)b * 65536;
    for (int ks = 0; ks < 8; ++ks) {
        int cb = ks * 32 + lk;
        // A-frags: Mg rows (bf16, row-major, L2-resident)
        short8 afr[4];
#pragma unroll
        for (int mi = 0; mi < 4; ++mi) {
            int r = w * 64 + mi * 16 + lr;
            afr[mi] = *(const short8*)(Mb + (size_t)r * 256 + cb);
        }
        // B-frags: X^T built from fp32 LDS (8 strided reads + cvt per frag)
        short8 bfr[4];
#pragma unroll
        for (int ni = 0; ni < 4; ++ni) {
            int nn = ni * 16 + lr;
            short8 bb;
#pragma unroll
            for (int m = 0; m < 8; ++m) {
                float xv = XL[(cb + m) * 64 + nn];
                bb[m] = (short)bf16bits(xv);
            }
            bfr[ni] = bb;
        }
#pragma unroll
        for (int mi = 0; mi < 4; ++mi)
#pragma unroll
            for (int ni = 0; ni < 4; ++ni)
                acc[mi][ni] = __builtin_amdgcn_mfma_f32_16x16x32_bf16(afr[mi], bfr[ni], acc[mi][ni], 0, 0, 0);
    }
    // epilogue: + Tvec[r] + residual X (fp32, from LDS)
    int lr4 = (lane >> 4) * 4;
    int lc = lane & 15;
#pragma unroll
    for (int mi = 0; mi < 4; ++mi) {
#pragma unroll
        for (int j = 0; j < 4; ++j) {
            int r = w * 64 + mi * 16 + lr4 + j;
            float tv = Tvec[b * 256 + r];
            float* yr = Y + ((size_t)(b * 256 + r)) * NPIX + n0;
#pragma unroll
            for (int ni = 0; ni < 4; ++ni) {
                int nn = ni * 16 + lc;
                yr[nn] = acc[mi][ni][j] + tv + XL[r * 64 + nn];
            }
        }
    }
}

extern "C" void kernel_launch(void* const* d_in, const int* in_sizes, int n_in,
                              void* d_out, int out_size, void* d_ws, size_t ws_size,
                              hipStream_t stream) {
    (void)in_sizes; (void)n_in; (void)out_size; (void)ws_size;
    const float* X     = (const float*)d_in[0];
    const float* Wq    = (const float*)d_in[1];
    const float* bq    = (const float*)d_in[2];
    const float* Wk    = (const float*)d_in[3];
    const float* bk    = (const float*)d_in[4];
    const float* Wv    = (const float*)d_in[5];
    const float* bv    = (const float*)d_in[6];
    const float* gamma = (const float*)d_in[7];
    float* Y  = (float*)d_out;
    float* ws = (float*)d_ws;

    float* G    = ws + WS_G;
    float* S    = ws + WS_S;
    float* Pq   = ws + WS_PQ;
    float* U    = ws + WS_U;
    float* Wvec = ws + WS_W;
    float* WkT  = ws + WS_WKT;
    float* WqT  = ws + WS_WQT;
    unsigned short* Mgb = (unsigned short*)(ws + WS_MGBF);
    float* Tvec = ws + WS_TV;
    float* Part = Y;   // reuse 134MB output buffer as 64MB Gram-partial scratch
                       // (consumed by k_reduce before k_gemmC overwrites it)

    k_misc<<<dim3(256), dim3(256), 0, stream>>>(Wq, Wk, WqT, WkT, S);
    k_gemmA<<<dim3(256), dim3(512), 0, stream>>>(X, Part, S);
    k_reduce<<<dim3(256), dim3(256), 0, stream>>>(Part, G);
    k_B1<<<dim3(128), dim3(256), 0, stream>>>(Wq, G, Pq);
    k_uw<<<dim3(8), dim3(256), 0, stream>>>(WqT, WkT, S, U, Wvec);
    k_B2<<<dim3(32), dim3(256), 0, stream>>>(Pq, WkT, bq, bk, bv, Wv, U, Wvec, gamma, Mgb, Tvec);
    k_gemmC<<<dim3(2048), dim3(256), 0, stream>>>(X, Mgb, Tvec, Y);
}

// Round 4
// 574.176 us; speedup vs baseline: 1.8214x; 1.0080x over previous
//
#include <hip/hip_runtime.h>
#include <stdint.h>

#define NB 8
#define NC 256
#define NPIX 16384

typedef float f32x4 __attribute__((ext_vector_type(4)));
typedef short short8 __attribute__((ext_vector_type(8)));

// workspace layout in floats
#define WS_G     0          // 8*256*256
#define WS_S     524288     // 8*256
#define WS_PQ    526336     // 8*256*256
#define WS_U     1050624    // 8*256
#define WS_W     1052672    // 8*256
#define WS_WKT   1054720    // 256*256
#define WS_WQT   1120256    // 256*256
#define WS_MGBF  1185792    // 8*256*256 bf16 = 262144 floats
#define WS_TV    1447936    // 8*256
// total 1449984 floats = 5.8 MB

__device__ __forceinline__ void splitbf(float f, unsigned short& h, unsigned short& l) {
    __bf16 hb = (__bf16)f;
    float r = f - (float)hb;
    __bf16 lb = (__bf16)r;
    h = __builtin_bit_cast(unsigned short, hb);
    l = __builtin_bit_cast(unsigned short, lb);
}

__device__ __forceinline__ unsigned short bf16bits(float f) {
    return __builtin_bit_cast(unsigned short, (__bf16)f);
}

// ---------------- misc: transpose Wq & Wk, zero S ----------------
__global__ void k_misc(const float* __restrict__ Wq, const float* __restrict__ Wk,
                       float* __restrict__ WqT, float* __restrict__ WkT,
                       float* __restrict__ S) {
    int c = blockIdx.x, t = threadIdx.x;
    WqT[c * 256 + t] = Wq[t * 256 + c];
    WkT[c * 256 + t] = Wk[t * 256 + c];
    if (c < 8) S[c * 256 + t] = 0.f;
}

// ---------------- Gram: per (b, chunk) partial G = X X^T, 256x256 tile ----------------
__global__ __launch_bounds__(512, 2) void k_gemmA(const float* __restrict__ X,
                                                  float* __restrict__ Pout,
                                                  float* __restrict__ S) {
    int bx = blockIdx.x;            // 256 blocks = 8 b * 32 chunks
    int b = bx >> 5, ch = bx & 31;  // chunk = 512 pixels
    int tid = threadIdx.x;
    int lane = tid & 63;
    int w = tid >> 6;               // 8 waves: 2 x 4
    int wrow = w >> 2, wcol = w & 3;
    int lrow = lane & 15;
    int lk8 = (lane >> 4) << 3;

    __shared__ __align__(16) unsigned short Thi[256 * 64];
    __shared__ __align__(16) unsigned short Tlo[256 * 64];

    f32x4 zero4 = {0.f, 0.f, 0.f, 0.f};
    f32x4 acc[8][4];
#pragma unroll
    for (int mi = 0; mi < 8; ++mi)
#pragma unroll
        for (int ni = 0; ni < 4; ++ni) acc[mi][ni] = zero4;

    float rsum[8];
#pragma unroll
    for (int i = 0; i < 8; ++i) rsum[i] = 0.f;

    const float* Xb = X + (size_t)b * NC * NPIX + ch * 512;

    for (int kk = 0; kk < 8; ++kk) {   // 8 * BK64 = 512 pixels
        __syncthreads();
#pragma unroll
        for (int i = 0; i < 8; ++i) {
            int flat = tid + i * 512;       // 0..4095 float4
            int r = flat >> 4;
            int k4 = flat & 15;
            float4 v = *(const float4*)(Xb + (size_t)r * NPIX + kk * 64 + k4 * 4);
            rsum[i] += v.x + v.y + v.z + v.w;
            unsigned short h0, h1, h2, h3, l0, l1, l2, l3;
            splitbf(v.x, h0, l0); splitbf(v.y, h1, l1);
            splitbf(v.z, h2, l2); splitbf(v.w, h3, l3);
            int e0 = (r * 64 + k4 * 4) ^ ((r & 7) << 3);
            uint2 hu, lu;
            hu.x = (unsigned)h0 | ((unsigned)h1 << 16);
            hu.y = (unsigned)h2 | ((unsigned)h3 << 16);
            lu.x = (unsigned)l0 | ((unsigned)l1 << 16);
            lu.y = (unsigned)l2 | ((unsigned)l3 << 16);
            *(uint2*)&Thi[e0] = hu;
            *(uint2*)&Tlo[e0] = lu;
        }
        __syncthreads();
#pragma unroll
        for (int ks = 0; ks < 2; ++ks) {
            short8 bh[4], bl[4];
#pragma unroll
            for (int ni = 0; ni < 4; ++ni) {
                int row = wcol * 64 + ni * 16 + lrow;
                int e = (row * 64 + ks * 32 + lk8) ^ ((row & 7) << 3);
                bh[ni] = *(const short8*)&Thi[e];
                bl[ni] = *(const short8*)&Tlo[e];
            }
#pragma unroll
            for (int mi = 0; mi < 8; ++mi) {
                int row = wrow * 128 + mi * 16 + lrow;
                int e = (row * 64 + ks * 32 + lk8) ^ ((row & 7) << 3);
                short8 ah = *(const short8*)&Thi[e];
                short8 al = *(const short8*)&Tlo[e];
#pragma unroll
                for (int ni = 0; ni < 4; ++ni) {
                    acc[mi][ni] = __builtin_amdgcn_mfma_f32_16x16x32_bf16(ah, bh[ni], acc[mi][ni], 0, 0, 0);
                    acc[mi][ni] = __builtin_amdgcn_mfma_f32_16x16x32_bf16(ah, bl[ni], acc[mi][ni], 0, 0, 0);
                    acc[mi][ni] = __builtin_amdgcn_mfma_f32_16x16x32_bf16(al, bh[ni], acc[mi][ni], 0, 0, 0);
                }
            }
        }
    }
    float* pb = Pout + ((size_t)(b * 32 + ch)) * 65536;
    int lr4 = (lane >> 4) << 2;
    int lc = lane & 15;
#pragma unroll
    for (int mi = 0; mi < 8; ++mi)
#pragma unroll
        for (int ni = 0; ni < 4; ++ni)
#pragma unroll
            for (int j = 0; j < 4; ++j) {
                int gr = wrow * 128 + mi * 16 + lr4 + j;
                int gc = wcol * 64 + ni * 16 + lc;
                pb[gr * 256 + gc] = acc[mi][ni][j];
            }
#pragma unroll
    for (int i = 0; i < 8; ++i) {
        float rs = rsum[i];
        rs += __shfl_down(rs, 8, 16);
        rs += __shfl_down(rs, 4, 16);
        rs += __shfl_down(rs, 2, 16);
        rs += __shfl_down(rs, 1, 16);
        if ((tid & 15) == 0)
            atomicAdd(&S[b * 256 + (tid >> 4) + 32 * i], rs);
    }
}

// ---------------- reduce 32 chunk-partials -> G ----------------
__global__ void k_reduce(const float* __restrict__ Pin, float* __restrict__ G) {
    int bx = blockIdx.x;            // 256 = 8 b * 32 segs
    int b = bx >> 5, seg = bx & 31;
    int t = threadIdx.x;
#pragma unroll
    for (int k = 0; k < 8; ++k) {
        int i = seg * 2048 + k * 256 + t;
        float s = 0.f;
        for (int chk = 0; chk < 32; ++chk)
            s += Pin[((size_t)(b * 32 + chk)) * 65536 + i];
        G[(size_t)b * 65536 + i] = s;
    }
}

// ---------------- uw: u = Wq s, w = Wk s ----------------
__global__ void k_uw(const float* __restrict__ WqT, const float* __restrict__ WkT,
                     const float* __restrict__ S, float* __restrict__ U,
                     float* __restrict__ Wvec) {
    int b = blockIdx.x, d = threadIdx.x;
    __shared__ float sl[256];
    sl[d] = S[b * 256 + d];
    __syncthreads();
    float u = 0.f, w = 0.f;
    for (int c = 0; c < 256; ++c) {
        float sv = sl[c];
        u += WqT[c * 256 + d] * sv;
        w += WkT[c * 256 + d] * sv;
    }
    U[b * 256 + d] = u;
    Wvec[b * 256 + d] = w;
}

// ---------------- B1: Pq = Wq * G_b  (A in LDS broadcast, B float4 from global) ----------------
__global__ __launch_bounds__(256) void k_B1(const float* __restrict__ Wq,
                                            const float* __restrict__ G,
                                            float* __restrict__ Pq) {
    int bx = blockIdx.x;            // 128 = 8 b * 8 rt * 2 ct
    int b = bx >> 4, rt = (bx >> 1) & 7, ct = bx & 1;
    int t = threadIdx.x;
    int r = t >> 3, cg = t & 7;
    int Dbase = rt * 32, cbase = ct * 128;
    __shared__ float WqL[32][260];
#pragma unroll
    for (int i = 0; i < 8; ++i) {
        int f = t + i * 256;        // 2048 float4
        int row = f >> 6, c4 = (f & 63) * 4;
        *(float4*)&WqL[row][c4] = *(const float4*)(Wq + (size_t)(Dbase + row) * 256 + c4);
    }
    __syncthreads();
    float acc[16];
#pragma unroll
    for (int j = 0; j < 16; ++j) acc[j] = 0.f;
    const float* Gb = G + (size_t)b * 65536 + cbase + cg * 16;
    for (int c = 0; c < 256; ++c) {
        float p = WqL[r][c];
        const float* gr = Gb + (size_t)c * 256;
#pragma unroll
        for (int k = 0; k < 4; ++k) {
            float4 g = *(const float4*)(gr + k * 4);
            acc[4 * k + 0] += p * g.x;
            acc[4 * k + 1] += p * g.y;
            acc[4 * k + 2] += p * g.z;
            acc[4 * k + 3] += p * g.w;
        }
    }
    float* op = Pq + ((size_t)(b * 256 + Dbase + r)) * 256 + cbase + cg * 16;
#pragma unroll
    for (int k = 0; k < 4; ++k)
        *(float4*)(op + k * 4) = *(float4*)&acc[4 * k];
}

// ---------------- B2a: logits -> softmax -> attn (fp32), Tvec ----------------
__global__ __launch_bounds__(256) void k_B2a(const float* __restrict__ Pq,
                                             const float* __restrict__ WkT,
                                             const float* __restrict__ bq,
                                             const float* __restrict__ bk,
                                             const float* __restrict__ bv,
                                             const float* __restrict__ U,
                                             const float* __restrict__ Wvec,
                                             const float* __restrict__ gamma,
                                             float* __restrict__ Att,
                                             float* __restrict__ Tvec) {
    int bx = blockIdx.x;            // 64 = 8 b * 2 h * 4 rt
    int b = bx >> 3, h = (bx >> 2) & 1, rt = bx & 3;
    int t = threadIdx.x;
    int r = t >> 3, cg = t & 7;
    int Dbase = h * 128 + rt * 32;
    __shared__ float PqL[32][260];
#pragma unroll
    for (int i = 0; i < 8; ++i) {
        int f = t + i * 256;
        int row = f >> 6, c4 = (f & 63) * 4;
        *(float4*)&PqL[row][c4] = *(const float4*)(Pq + ((size_t)(b * 256 + Dbase + row)) * 256 + c4);
    }
    __syncthreads();
    float acc[16];
#pragma unroll
    for (int j = 0; j < 16; ++j) acc[j] = 0.f;
    const float* Kb = WkT + h * 128 + cg * 16;
    for (int c = 0; c < 256; ++c) {
        float p = PqL[r][c];
        const float* kr = Kb + (size_t)c * 256;
#pragma unroll
        for (int k = 0; k < 4; ++k) {
            float4 g = *(const float4*)(kr + k * 4);
            acc[4 * k + 0] += p * g.x;
            acc[4 * k + 1] += p * g.y;
            acc[4 * k + 2] += p * g.z;
            acc[4 * k + 3] += p * g.w;
        }
    }
    // rank-1 terms + row max
    int D = Dbase + r;
    float bqD = bq[D];
    float uD = U[b * 256 + D];
    float g0 = gamma[0];
    float m = -3.0e38f;
#pragma unroll
    for (int j = 0; j < 16; ++j) {
        int E = h * 128 + cg * 16 + j;
        float l = acc[j] + bqD * Wvec[b * 256 + E] + bk[E] * uD + 16384.f * bqD * bk[E];
        acc[j] = l;
        m = fmaxf(m, l);
    }
    m = fmaxf(m, __shfl_xor(m, 1, 8));
    m = fmaxf(m, __shfl_xor(m, 2, 8));
    m = fmaxf(m, __shfl_xor(m, 4, 8));
    float ss = 0.f;
#pragma unroll
    for (int j = 0; j < 16; ++j) {
        float e = __expf(acc[j] - m);
        acc[j] = e;
        ss += e;
    }
    ss += __shfl_xor(ss, 1, 8);
    ss += __shfl_xor(ss, 2, 8);
    ss += __shfl_xor(ss, 4, 8);
    float inv = 1.f / ss;
    float tv = 0.f;
    float* ar = Att + ((size_t)((b * 2 + h) * 128 + rt * 32 + r)) * 128 + cg * 16;
#pragma unroll
    for (int j = 0; j < 16; ++j) {
        float a = acc[j] * inv;
        acc[j] = a;
        tv += a * bv[h * 128 + cg * 16 + j];
    }
#pragma unroll
    for (int k = 0; k < 4; ++k)
        *(float4*)(ar + k * 4) = *(float4*)&acc[4 * k];
    tv += __shfl_xor(tv, 1, 8);
    tv += __shfl_xor(tv, 2, 8);
    tv += __shfl_xor(tv, 4, 8);
    if (cg == 0) Tvec[b * 256 + D] = g0 * tv;
}

// ---------------- B2b: Mg = gamma * attn * Wv (bf16 row-major) ----------------
__global__ __launch_bounds__(256) void k_B2b(const float* __restrict__ Att,
                                             const float* __restrict__ Wv,
                                             const float* __restrict__ gamma,
                                             unsigned short* __restrict__ Mgb) {
    int bx = blockIdx.x;            // 128 = 8 b * 8 dt * 2 ct
    int b = bx >> 4, dt = (bx >> 1) & 7, ct = bx & 1;
    int h = dt >> 2;
    int Dbase = dt * 32, cbase = ct * 128;   // Dbase = global D offset
    int dloc = (dt & 3) * 32;                 // D offset WITHIN head (Att layout)
    int t = threadIdx.x;
    int r = t >> 3, cg = t & 7;
    __shared__ float AL[32][132];
#pragma unroll
    for (int i = 0; i < 4; ++i) {
        int f = t + i * 256;        // 1024 float4
        int row = f >> 5, e4 = (f & 31) * 4;
        *(float4*)&AL[row][e4] = *(const float4*)(Att + ((size_t)((b * 2 + h) * 128 + dloc + row)) * 128 + e4);
    }
    __syncthreads();
    float acc[16];
#pragma unroll
    for (int j = 0; j < 16; ++j) acc[j] = 0.f;
    const float* Wb = Wv + (size_t)(h * 128) * 256 + cbase + cg * 16;
    for (int e = 0; e < 128; ++e) {
        float a = AL[r][e];
        const float* wr = Wb + (size_t)e * 256;
#pragma unroll
        for (int k = 0; k < 4; ++k) {
            float4 g = *(const float4*)(wr + k * 4);
            acc[4 * k + 0] += a * g.x;
            acc[4 * k + 1] += a * g.y;
            acc[4 * k + 2] += a * g.z;
            acc[4 * k + 3] += a * g.w;
        }
    }
    float g0 = gamma[0];
    unsigned int* Mp = (unsigned int*)(Mgb + ((size_t)(b * 256 + Dbase + r)) * 256 + cbase + cg * 16);
#pragma unroll
    for (int j = 0; j < 8; ++j) {
        unsigned short a0 = bf16bits(g0 * acc[2 * j]);
        unsigned short a1 = bf16bits(g0 * acc[2 * j + 1]);
        Mp[j] = (unsigned)a0 | ((unsigned)a1 << 16);
    }
}

// ---------------- apply: Y = Mg X + Tvec + X  (bf16 MFMA, fp32 residual from LDS) ----------------
__global__ __launch_bounds__(256, 2) void k_gemmC(const float* __restrict__ X,
                                                  const unsigned short* __restrict__ Mgb,
                                                  const float* __restrict__ Tvec,
                                                  float* __restrict__ Y) {
    int bx = blockIdx.x;            // 2048 = 8 b * 256 ntiles of 64 px
    int b = bx >> 8, nt = bx & 255;
    int n0 = nt * 64;
    int tid = threadIdx.x;
    int lane = tid & 63, w = tid >> 6;

    __shared__ float XL[256 * 64];

    const float* Xb = X + (size_t)b * NC * NPIX + n0;
#pragma unroll
    for (int i = 0; i < 16; ++i) {
        int flat = tid + i * 256;
        int c = flat >> 4;
        int n4 = (flat & 15) * 4;
        *(float4*)&XL[c * 64 + n4] = *(const float4*)(Xb + (size_t)c * NPIX + n4);
    }
    __syncthreads();

    int lr = lane & 15;
    int lk = (lane >> 4) * 8;

    f32x4 zero4 = {0.f, 0.f, 0.f, 0.f};
    f32x4 acc[4][4];
#pragma unroll
    for (int mi = 0; mi < 4; ++mi)
#pragma unroll
        for (int ni = 0; ni < 4; ++ni) acc[mi][ni] = zero4;

    const unsigned short* Mb = Mgb + (size_t)b * 65536;
    for (int ks = 0; ks < 8; ++ks) {
        int cb = ks * 32 + lk;
        short8 afr[4];
#pragma unroll
        for (int mi = 0; mi < 4; ++mi) {
            int r = w * 64 + mi * 16 + lr;
            afr[mi] = *(const short8*)(Mb + (size_t)r * 256 + cb);
        }
        short8 bfr[4];
#pragma unroll
        for (int ni = 0; ni < 4; ++ni) {
            int nn = ni * 16 + lr;
            short8 bb;
#pragma unroll
            for (int m = 0; m < 8; ++m) {
                float xv = XL[(cb + m) * 64 + nn];
                bb[m] = (short)bf16bits(xv);
            }
            bfr[ni] = bb;
        }
#pragma unroll
        for (int mi = 0; mi < 4; ++mi)
#pragma unroll
            for (int ni = 0; ni < 4; ++ni)
                acc[mi][ni] = __builtin_amdgcn_mfma_f32_16x16x32_bf16(afr[mi], bfr[ni], acc[mi][ni], 0, 0, 0);
    }
    int lr4 = (lane >> 4) * 4;
    int lc = lane & 15;
#pragma unroll
    for (int mi = 0; mi < 4; ++mi) {
#pragma unroll
        for (int j = 0; j < 4; ++j) {
            int r = w * 64 + mi * 16 + lr4 + j;
            float tv = Tvec[b * 256 + r];
            float* yr = Y + ((size_t)(b * 256 + r)) * NPIX + n0;
#pragma unroll
            for (int ni = 0; ni < 4; ++ni) {
                int nn = ni * 16 + lc;
                yr[nn] = acc[mi][ni][j] + tv + XL[r * 64 + nn];
            }
        }
    }
}

extern "C" void kernel_launch(void* const* d_in, const int* in_sizes, int n_in,
                              void* d_out, int out_size, void* d_ws, size_t ws_size,
                              hipStream_t stream) {
    (void)in_sizes; (void)n_in; (void)out_size; (void)ws_size;
    const float* X     = (const float*)d_in[0];
    const float* Wq    = (const float*)d_in[1];
    const float* bq    = (const float*)d_in[2];
    const float* Wk    = (const float*)d_in[3];
    const float* bk    = (const float*)d_in[4];
    const float* Wv    = (const float*)d_in[5];
    const float* bv    = (const float*)d_in[6];
    const float* gamma = (const float*)d_in[7];
    float* Y  = (float*)d_out;
    float* ws = (float*)d_ws;

    float* G    = ws + WS_G;
    float* S    = ws + WS_S;
    float* Pq   = ws + WS_PQ;
    float* U    = ws + WS_U;
    float* Wvec = ws + WS_W;
    float* WkT  = ws + WS_WKT;
    float* WqT  = ws + WS_WQT;
    unsigned short* Mgb = (unsigned short*)(ws + WS_MGBF);
    float* Tvec = ws + WS_TV;
    float* Part = Y;                      // Y[0 .. 16.7M floats): Gram partial scratch
    float* Att  = Y + (33554432 - 262144); // Y tail: attn scratch (1 MB), consumed pre-gemmC

    k_misc<<<dim3(256), dim3(256), 0, stream>>>(Wq, Wk, WqT, WkT, S);
    k_gemmA<<<dim3(256), dim3(512), 0, stream>>>(X, Part, S);
    k_reduce<<<dim3(256), dim3(256), 0, stream>>>(Part, G);
    k_uw<<<dim3(8), dim3(256), 0, stream>>>(WqT, WkT, S, U, Wvec);
    k_B1<<<dim3(128), dim3(256), 0, stream>>>(Wq, G, Pq);
    k_B2a<<<dim3(64), dim3(256), 0, stream>>>(Pq, WkT, bq, bk, bv, U, Wvec, gamma, Att, Tvec);
    k_B2b<<<dim3(128), dim3(256), 0, stream>>>(Att, Wv, gamma, Mgb);
    k_gemmC<<<dim3(2048), dim3(256), 0, stream>>>(X, Mgb, Tvec, Y);
}

// Round 5
// 418.953 us; speedup vs baseline: 2.4962x; 1.3705x over previous
//
#include <hip/hip_runtime.h>
#include <stdint.h>

#define NB 8
#define NC 256
#define NPIX 16384

typedef float f32x4 __attribute__((ext_vector_type(4)));
typedef short short8 __attribute__((ext_vector_type(8)));

// workspace layout in floats
#define WS_G     0          // 8*256*256
#define WS_S     524288     // 8*256
#define WS_U     526336     // 8*256
#define WS_W     528384     // 8*256
#define WS_WKT   530432     // 256*256
#define WS_WQT   595968     // 256*256
#define WS_MGBF  661504     // 8*256*256 bf16 = 262144 floats
#define WS_TV    923648     // 8*256
// total ~3.7 MB

__device__ __forceinline__ void splitbf(float f, unsigned short& h, unsigned short& l) {
    __bf16 hb = (__bf16)f;
    float r = f - (float)hb;
    __bf16 lb = (__bf16)r;
    h = __builtin_bit_cast(unsigned short, hb);
    l = __builtin_bit_cast(unsigned short, lb);
}

__device__ __forceinline__ unsigned short bf16bits(float f) {
    return __builtin_bit_cast(unsigned short, (__bf16)f);
}

// ---------------- misc: transpose Wq & Wk, zero S ----------------
__global__ void k_misc(const float* __restrict__ Wq, const float* __restrict__ Wk,
                       float* __restrict__ WqT, float* __restrict__ WkT,
                       float* __restrict__ S) {
    int c = blockIdx.x, t = threadIdx.x;
    WqT[c * 256 + t] = Wq[t * 256 + c];
    WkT[c * 256 + t] = Wk[t * 256 + c];
    if (c < 8) S[c * 256 + t] = 0.f;
}

// ---------------- Gram: per (b, chunk=256px) partial G = X X^T ----------------
// hi/lo bf16 split, 3 MFMA passes ~ fp32. 512 blocks -> 2 blocks/CU so stage/MFMA overlap.
__global__ __launch_bounds__(512, 2) void k_gemmA(const float* __restrict__ X,
                                                  float* __restrict__ Pout,
                                                  float* __restrict__ S) {
    int bx = blockIdx.x;            // 512 blocks = 8 b * 64 chunks
    int b = bx >> 6, ch = bx & 63;  // chunk = 256 pixels
    int tid = threadIdx.x;
    int lane = tid & 63;
    int w = tid >> 6;               // 8 waves: 2 x 4
    int wrow = w >> 2, wcol = w & 3;
    int lrow = lane & 15;
    int lk8 = (lane >> 4) << 3;

    __shared__ __align__(16) unsigned short Thi[256 * 64];
    __shared__ __align__(16) unsigned short Tlo[256 * 64];

    f32x4 zero4 = {0.f, 0.f, 0.f, 0.f};
    f32x4 acc[8][4];
#pragma unroll
    for (int mi = 0; mi < 8; ++mi)
#pragma unroll
        for (int ni = 0; ni < 4; ++ni) acc[mi][ni] = zero4;

    float rsum[8];
#pragma unroll
    for (int i = 0; i < 8; ++i) rsum[i] = 0.f;

    const float* Xb = X + (size_t)b * NC * NPIX + ch * 256;

    for (int kk = 0; kk < 4; ++kk) {   // 4 * 64 = 256 pixels
        __syncthreads();
#pragma unroll
        for (int i = 0; i < 8; ++i) {
            int flat = tid + i * 512;       // 0..4095 float4
            int r = flat >> 4;
            int k4 = flat & 15;
            float4 v = *(const float4*)(Xb + (size_t)r * NPIX + kk * 64 + k4 * 4);
            rsum[i] += v.x + v.y + v.z + v.w;
            unsigned short h0, h1, h2, h3, l0, l1, l2, l3;
            splitbf(v.x, h0, l0); splitbf(v.y, h1, l1);
            splitbf(v.z, h2, l2); splitbf(v.w, h3, l3);
            int e0 = (r * 64 + k4 * 4) ^ ((r & 7) << 3);
            uint2 hu, lu;
            hu.x = (unsigned)h0 | ((unsigned)h1 << 16);
            hu.y = (unsigned)h2 | ((unsigned)h3 << 16);
            lu.x = (unsigned)l0 | ((unsigned)l1 << 16);
            lu.y = (unsigned)l2 | ((unsigned)l3 << 16);
            *(uint2*)&Thi[e0] = hu;
            *(uint2*)&Tlo[e0] = lu;
        }
        __syncthreads();
#pragma unroll
        for (int ks = 0; ks < 2; ++ks) {
            short8 bh[4], bl[4];
#pragma unroll
            for (int ni = 0; ni < 4; ++ni) {
                int row = wcol * 64 + ni * 16 + lrow;
                int e = (row * 64 + ks * 32 + lk8) ^ ((row & 7) << 3);
                bh[ni] = *(const short8*)&Thi[e];
                bl[ni] = *(const short8*)&Tlo[e];
            }
#pragma unroll
            for (int mi = 0; mi < 8; ++mi) {
                int row = wrow * 128 + mi * 16 + lrow;
                int e = (row * 64 + ks * 32 + lk8) ^ ((row & 7) << 3);
                short8 ah = *(const short8*)&Thi[e];
                short8 al = *(const short8*)&Tlo[e];
#pragma unroll
                for (int ni = 0; ni < 4; ++ni) {
                    acc[mi][ni] = __builtin_amdgcn_mfma_f32_16x16x32_bf16(ah, bh[ni], acc[mi][ni], 0, 0, 0);
                    acc[mi][ni] = __builtin_amdgcn_mfma_f32_16x16x32_bf16(ah, bl[ni], acc[mi][ni], 0, 0, 0);
                    acc[mi][ni] = __builtin_amdgcn_mfma_f32_16x16x32_bf16(al, bh[ni], acc[mi][ni], 0, 0, 0);
                }
            }
        }
    }
    float* pb = Pout + ((size_t)(b * 64 + ch)) * 65536;
    int lr4 = (lane >> 4) << 2;
    int lc = lane & 15;
#pragma unroll
    for (int mi = 0; mi < 8; ++mi)
#pragma unroll
        for (int ni = 0; ni < 4; ++ni)
#pragma unroll
            for (int j = 0; j < 4; ++j) {
                int gr = wrow * 128 + mi * 16 + lr4 + j;
                int gc = wcol * 64 + ni * 16 + lc;
                pb[gr * 256 + gc] = acc[mi][ni][j];
            }
#pragma unroll
    for (int i = 0; i < 8; ++i) {
        float rs = rsum[i];
        rs += __shfl_down(rs, 8, 16);
        rs += __shfl_down(rs, 4, 16);
        rs += __shfl_down(rs, 2, 16);
        rs += __shfl_down(rs, 1, 16);
        if ((tid & 15) == 0)
            atomicAdd(&S[b * 256 + (tid >> 4) + 32 * i], rs);
    }
}

// ---------------- reduce 64 chunk-partials -> G ----------------
__global__ void k_reduce(const float* __restrict__ Pin, float* __restrict__ G) {
    int bx = blockIdx.x;            // 256 = 8 b * 32 segs
    int b = bx >> 5, seg = bx & 31;
    int t = threadIdx.x;
#pragma unroll
    for (int k = 0; k < 8; ++k) {
        int i = seg * 2048 + k * 256 + t;
        float s = 0.f;
        for (int chk = 0; chk < 64; ++chk)
            s += Pin[((size_t)(b * 64 + chk)) * 65536 + i];
        G[(size_t)b * 65536 + i] = s;
    }
}

// ---------------- uw: u = Wq s, w = Wk s ----------------
__global__ void k_uw(const float* __restrict__ WqT, const float* __restrict__ WkT,
                     const float* __restrict__ S, float* __restrict__ U,
                     float* __restrict__ Wvec) {
    int b = blockIdx.x, d = threadIdx.x;
    __shared__ float sl[256];
    sl[d] = S[b * 256 + d];
    __syncthreads();
    float u = 0.f, w = 0.f;
    for (int c = 0; c < 256; ++c) {
        float sv = sl[c];
        u += WqT[c * 256 + d] * sv;
        w += WkT[c * 256 + d] * sv;
    }
    U[b * 256 + d] = u;
    Wvec[b * 256 + d] = w;
}

// ---------------- fused middle chain: per (b, 16-row D-tile) ----------------
// Pq = Wq_tile * G_b ; logits = Pq * WkT_head + rank1 ; softmax ; Mg = gamma*attn*Wv_head ; Tvec
__global__ __launch_bounds__(256) void k_mid(const float* __restrict__ Wq,
                                             const float* __restrict__ G,
                                             const float* __restrict__ WkT,
                                             const float* __restrict__ Wv,
                                             const float* __restrict__ bq,
                                             const float* __restrict__ bk,
                                             const float* __restrict__ bv,
                                             const float* __restrict__ U,
                                             const float* __restrict__ Wvec,
                                             const float* __restrict__ gamma,
                                             unsigned short* __restrict__ Mgb,
                                             float* __restrict__ Tvec) {
    int bx = blockIdx.x;            // 128 = 8 b * 16 dt
    int b = bx >> 4, dt = bx & 15;
    int Dbase = dt * 16;
    int h = dt >> 3;                // head
    int t = threadIdx.x;
    int rg = t >> 5;                // 0..7 row-group
    int cg = t & 31;                // 0..31 col-group
    int r0 = rg * 2, r1 = r0 + 1;

    // LDS: [0,4096) WqL[16][256] -> later AttL[16][128]
    //      [4096,8192) PqL[16][256]
    //      [8192,24576) GL[64][256] -> WkL[128][128] -> WvL[128][128]
    __shared__ __align__(16) float smem[24576];
    float* WqL = smem;
    float* PqL = smem + 4096;
    float* BIG = smem + 8192;
    float* AttL = smem;

    // stage WqL[16][256]
#pragma unroll
    for (int i = 0; i < 4; ++i) {
        int f = t + i * 256;        // 1024 float4
        int row = f >> 6, c4 = (f & 63) * 4;
        *(float4*)&WqL[row * 256 + c4] = *(const float4*)(Wq + (size_t)(Dbase + row) * 256 + c4);
    }

    // ---- Phase B: Pq_tile = Wq_tile x G_b, 4 panels of 64 G-rows ----
    f32x4 pqA0 = {0,0,0,0}, pqA1 = pqA0, pqB0 = pqA0, pqB1 = pqA0;
    const float* Gb = G + (size_t)b * 65536;
    for (int p = 0; p < 4; ++p) {
        __syncthreads();
#pragma unroll
        for (int i = 0; i < 16; ++i) {
            int f = t + i * 256;    // 4096 float4
            int row = f >> 6, c4 = (f & 63) * 4;
            *(float4*)&BIG[row * 256 + c4] = *(const float4*)(Gb + (size_t)(p * 64 + row) * 256 + c4);
        }
        __syncthreads();
#pragma unroll 2
        for (int c = 0; c < 64; ++c) {
            float wq0 = WqL[r0 * 256 + p * 64 + c];
            float wq1 = WqL[r1 * 256 + p * 64 + c];
            f32x4 ga = *(const f32x4*)&BIG[c * 256 + cg * 4];
            f32x4 gb = *(const f32x4*)&BIG[c * 256 + 128 + cg * 4];
            pqA0 += wq0 * ga; pqB0 += wq0 * gb;
            pqA1 += wq1 * ga; pqB1 += wq1 * gb;
        }
    }
    __syncthreads();
    *(f32x4*)&PqL[r0 * 256 + cg * 4]       = pqA0;
    *(f32x4*)&PqL[r0 * 256 + 128 + cg * 4] = pqB0;
    *(f32x4*)&PqL[r1 * 256 + cg * 4]       = pqA1;
    *(f32x4*)&PqL[r1 * 256 + 128 + cg * 4] = pqB1;
    __syncthreads();

    // ---- Phase C: logits[16][128] = Pq_tile x WkT[:, head], 2 panels of 128 c' ----
    f32x4 l0 = {0,0,0,0}, l1 = l0;
    for (int q = 0; q < 2; ++q) {
        if (q) __syncthreads();
#pragma unroll
        for (int i = 0; i < 16; ++i) {
            int f = t + i * 256;    // 4096 float4
            int row = f >> 5, c4 = (f & 31) * 4;
            *(float4*)&BIG[row * 128 + c4] = *(const float4*)(WkT + (size_t)(q * 128 + row) * 256 + h * 128 + c4);
        }
        __syncthreads();
#pragma unroll 2
        for (int c = 0; c < 128; ++c) {
            float p0 = PqL[r0 * 256 + q * 128 + c];
            float p1 = PqL[r1 * 256 + q * 128 + c];
            f32x4 kv = *(const f32x4*)&BIG[c * 128 + cg * 4];
            l0 += p0 * kv;
            l1 += p1 * kv;
        }
    }

    // ---- Phase D: rank-1 terms + softmax over 32 lanes (each row spread over lanes) ----
    int D0 = Dbase + r0, D1 = Dbase + r1;
    float bq0 = bq[D0], bq1 = bq[D1];
    float u0 = U[b * 256 + D0], u1 = U[b * 256 + D1];
    float g0 = gamma[0];
    float m0 = -3.0e38f, m1 = -3.0e38f;
#pragma unroll
    for (int j = 0; j < 4; ++j) {
        int E = h * 128 + cg * 4 + j;
        float wv = Wvec[b * 256 + E];
        float bkE = bk[E];
        float t0 = l0[j] + bq0 * wv + bkE * u0 + 16384.f * bq0 * bkE;
        float t1 = l1[j] + bq1 * wv + bkE * u1 + 16384.f * bq1 * bkE;
        l0[j] = t0; l1[j] = t1;
        m0 = fmaxf(m0, t0); m1 = fmaxf(m1, t1);
    }
#pragma unroll
    for (int k = 1; k < 32; k <<= 1) {
        m0 = fmaxf(m0, __shfl_xor(m0, k, 32));
        m1 = fmaxf(m1, __shfl_xor(m1, k, 32));
    }
    float s0 = 0.f, s1 = 0.f;
#pragma unroll
    for (int j = 0; j < 4; ++j) {
        float e0 = __expf(l0[j] - m0);
        float e1 = __expf(l1[j] - m1);
        l0[j] = e0; l1[j] = e1;
        s0 += e0; s1 += e1;
    }
#pragma unroll
    for (int k = 1; k < 32; k <<= 1) {
        s0 += __shfl_xor(s0, k, 32);
        s1 += __shfl_xor(s1, k, 32);
    }
    float inv0 = 1.f / s0, inv1 = 1.f / s1;
    float tv0 = 0.f, tv1 = 0.f;
#pragma unroll
    for (int j = 0; j < 4; ++j) {
        float a0 = l0[j] * inv0;
        float a1 = l1[j] * inv1;
        l0[j] = a0; l1[j] = a1;
        float bvE = bv[h * 128 + cg * 4 + j];
        tv0 += a0 * bvE; tv1 += a1 * bvE;
    }
#pragma unroll
    for (int k = 1; k < 32; k <<= 1) {
        tv0 += __shfl_xor(tv0, k, 32);
        tv1 += __shfl_xor(tv1, k, 32);
    }
    __syncthreads();   // WqL dead; AttL aliases it
    *(f32x4*)&AttL[r0 * 128 + cg * 4] = l0;
    *(f32x4*)&AttL[r1 * 128 + cg * 4] = l1;
    if (cg == 0) {
        Tvec[b * 256 + D0] = g0 * tv0;
        Tvec[b * 256 + D1] = g0 * tv1;
    }

    // ---- Phase E: Mg = gamma * attn x Wv[head rows], 2 col-halves ----
    for (int q2 = 0; q2 < 2; ++q2) {
        __syncthreads();
#pragma unroll
        for (int i = 0; i < 16; ++i) {
            int f = t + i * 256;
            int row = f >> 5, c4 = (f & 31) * 4;
            *(float4*)&BIG[row * 128 + c4] = *(const float4*)(Wv + (size_t)(h * 128 + row) * 256 + q2 * 128 + c4);
        }
        __syncthreads();
        f32x4 mg0 = {0,0,0,0}, mg1 = mg0;
#pragma unroll 2
        for (int e = 0; e < 128; ++e) {
            float a0 = AttL[r0 * 128 + e];
            float a1 = AttL[r1 * 128 + e];
            f32x4 wv = *(const f32x4*)&BIG[e * 128 + cg * 4];
            mg0 += a0 * wv;
            mg1 += a1 * wv;
        }
        uint2 w0, w1;
        w0.x = (unsigned)bf16bits(g0 * mg0[0]) | ((unsigned)bf16bits(g0 * mg0[1]) << 16);
        w0.y = (unsigned)bf16bits(g0 * mg0[2]) | ((unsigned)bf16bits(g0 * mg0[3]) << 16);
        w1.x = (unsigned)bf16bits(g0 * mg1[0]) | ((unsigned)bf16bits(g0 * mg1[1]) << 16);
        w1.y = (unsigned)bf16bits(g0 * mg1[2]) | ((unsigned)bf16bits(g0 * mg1[3]) << 16);
        *(uint2*)(Mgb + ((size_t)(b * 256 + D0)) * 256 + q2 * 128 + cg * 4) = w0;
        *(uint2*)(Mgb + ((size_t)(b * 256 + D1)) * 256 + q2 * 128 + cg * 4) = w1;
    }
}

// ---------------- apply: Y = Mg X + Tvec + X  (bf16 MFMA, fp32 residual from LDS) ----------------
__global__ __launch_bounds__(256, 2) void k_gemmC(const float* __restrict__ X,
                                                  const unsigned short* __restrict__ Mgb,
                                                  const float* __restrict__ Tvec,
                                                  float* __restrict__ Y) {
    int bx = blockIdx.x;            // 2048 = 8 b * 256 ntiles of 64 px
    int b = bx >> 8, nt = bx & 255;
    int n0 = nt * 64;
    int tid = threadIdx.x;
    int lane = tid & 63, w = tid >> 6;

    __shared__ float XL[256 * 64];

    const float* Xb = X + (size_t)b * NC * NPIX + n0;
#pragma unroll
    for (int i = 0; i < 16; ++i) {
        int flat = tid + i * 256;
        int c = flat >> 4;
        int n4 = (flat & 15) * 4;
        *(float4*)&XL[c * 64 + n4] = *(const float4*)(Xb + (size_t)c * NPIX + n4);
    }
    __syncthreads();

    int lr = lane & 15;
    int lk = (lane >> 4) * 8;

    f32x4 zero4 = {0.f, 0.f, 0.f, 0.f};
    f32x4 acc[4][4];
#pragma unroll
    for (int mi = 0; mi < 4; ++mi)
#pragma unroll
        for (int ni = 0; ni < 4; ++ni) acc[mi][ni] = zero4;

    const unsigned short* Mb = Mgb + (size_t)b * 65536;
    for (int ks = 0; ks < 8; ++ks) {
        int cb = ks * 32 + lk;
        short8 afr[4];
#pragma unroll
        for (int mi = 0; mi < 4; ++mi) {
            int r = w * 64 + mi * 16 + lr;
            afr[mi] = *(const short8*)(Mb + (size_t)r * 256 + cb);
        }
        short8 bfr[4];
#pragma unroll
        for (int ni = 0; ni < 4; ++ni) {
            int nn = ni * 16 + lr;
            short8 bb;
#pragma unroll
            for (int m = 0; m < 8; ++m) {
                float xv = XL[(cb + m) * 64 + nn];
                bb[m] = (short)bf16bits(xv);
            }
            bfr[ni] = bb;
        }
#pragma unroll
        for (int mi = 0; mi < 4; ++mi)
#pragma unroll
            for (int ni = 0; ni < 4; ++ni)
                acc[mi][ni] = __builtin_amdgcn_mfma_f32_16x16x32_bf16(afr[mi], bfr[ni], acc[mi][ni], 0, 0, 0);
    }
    int lr4 = (lane >> 4) * 4;
    int lc = lane & 15;
#pragma unroll
    for (int mi = 0; mi < 4; ++mi) {
#pragma unroll
        for (int j = 0; j < 4; ++j) {
            int r = w * 64 + mi * 16 + lr4 + j;
            float tv = Tvec[b * 256 + r];
            float* yr = Y + ((size_t)(b * 256 + r)) * NPIX + n0;
#pragma unroll
            for (int ni = 0; ni < 4; ++ni) {
                int nn = ni * 16 + lc;
                yr[nn] = acc[mi][ni][j] + tv + XL[r * 64 + nn];
            }
        }
    }
}

extern "C" void kernel_launch(void* const* d_in, const int* in_sizes, int n_in,
                              void* d_out, int out_size, void* d_ws, size_t ws_size,
                              hipStream_t stream) {
    (void)in_sizes; (void)n_in; (void)out_size; (void)ws_size;
    const float* X     = (const float*)d_in[0];
    const float* Wq    = (const float*)d_in[1];
    const float* bq    = (const float*)d_in[2];
    const float* Wk    = (const float*)d_in[3];
    const float* bk    = (const float*)d_in[4];
    const float* Wv    = (const float*)d_in[5];
    const float* bv    = (const float*)d_in[6];
    const float* gamma = (const float*)d_in[7];
    float* Y  = (float*)d_out;
    float* ws = (float*)d_ws;

    float* G    = ws + WS_G;
    float* S    = ws + WS_S;
    float* U    = ws + WS_U;
    float* Wvec = ws + WS_W;
    float* WkT  = ws + WS_WKT;
    float* WqT  = ws + WS_WQT;
    unsigned short* Mgb = (unsigned short*)(ws + WS_MGBF);
    float* Tvec = ws + WS_TV;
    float* Part = Y;   // Y (33.55M floats) == exactly 512 x 65536 Gram-partial slots;
                       // dead after k_reduce, rewritten by k_gemmC

    k_misc<<<dim3(256), dim3(256), 0, stream>>>(Wq, Wk, WqT, WkT, S);
    k_gemmA<<<dim3(512), dim3(512), 0, stream>>>(X, Part, S);
    k_reduce<<<dim3(256), dim3(256), 0, stream>>>(Part, G);
    k_uw<<<dim3(8), dim3(256), 0, stream>>>(WqT, WkT, S, U, Wvec);
    k_mid<<<dim3(128), dim3(256), 0, stream>>>(Wq, G, WkT, Wv, bq, bk, bv, U, Wvec, gamma, Mgb, Tvec);
    k_gemmC<<<dim3(2048), dim3(256), 0, stream>>>(X, Mgb, Tvec, Y);
}

// Round 7
// 372.209 us; speedup vs baseline: 2.8097x; 1.1256x over previous
//
#include <hip/hip_runtime.h>
#include <stdint.h>

#define NB 8
#define NC 256
#define NPIX 16384

typedef float f32x4 __attribute__((ext_vector_type(4)));
typedef short short8 __attribute__((ext_vector_type(8)));

// workspace layout in floats
#define WS_G     0          // 8*256*256
#define WS_S     524288     // 8*256
#define WS_U     526336     // 8*256
#define WS_W     528384     // 8*256
#define WS_WKT   530432     // 256*256
#define WS_WQT   595968     // 256*256
#define WS_MGBF  661504     // 8*256*256 bf16 = 262144 floats
#define WS_TV    923648     // 8*256
// total ~3.7 MB

__device__ __forceinline__ void splitbf(float f, unsigned short& h, unsigned short& l) {
    __bf16 hb = (__bf16)f;
    float r = f - (float)hb;
    __bf16 lb = (__bf16)r;
    h = __builtin_bit_cast(unsigned short, hb);
    l = __builtin_bit_cast(unsigned short, lb);
}

__device__ __forceinline__ unsigned short bf16bits(float f) {
    return __builtin_bit_cast(unsigned short, (__bf16)f);
}

// ---------------- misc: transpose Wq & Wk, zero S ----------------
__global__ void k_misc(const float* __restrict__ Wq, const float* __restrict__ Wk,
                       float* __restrict__ WqT, float* __restrict__ WkT,
                       float* __restrict__ S) {
    int c = blockIdx.x, t = threadIdx.x;
    WqT[c * 256 + t] = Wq[t * 256 + c];
    WkT[c * 256 + t] = Wk[t * 256 + c];
    if (c < 8) S[c * 256 + t] = 0.f;
}

// ---------------- Gram: per (b, chunk=512px) partial G = X X^T ----------------
// hi/lo bf16 split, 3 MFMA passes ~ fp32.
// Double-buffered LDS K-tiles (64 px) + register prefetch: stage(k+1) overlaps MFMA(k).
__global__ __launch_bounds__(512, 2) void k_gemmA(const float* __restrict__ X,
                                                  float* __restrict__ Pout,
                                                  float* __restrict__ S) {
    int bx = blockIdx.x;            // 256 blocks = 8 b * 32 chunks
    int b = bx >> 5, ch = bx & 31;  // chunk = 512 pixels
    int tid = threadIdx.x;
    int lane = tid & 63;
    int w = tid >> 6;               // 8 waves: 2 x 4
    int wrow = w >> 2, wcol = w & 3;
    int lrow = lane & 15;
    int lk8 = (lane >> 4) << 3;

    __shared__ __align__(16) unsigned short Thi[2][16384];   // 2 x 256 rows x 64 k
    __shared__ __align__(16) unsigned short Tlo[2][16384];   // total 128 KB

    f32x4 zero4 = {0.f, 0.f, 0.f, 0.f};
    f32x4 acc[8][4];
#pragma unroll
    for (int mi = 0; mi < 8; ++mi)
#pragma unroll
        for (int ni = 0; ni < 4; ++ni) acc[mi][ni] = zero4;

    float rsum[8];
#pragma unroll
    for (int i = 0; i < 8; ++i) rsum[i] = 0.f;

    const float* Xb = X + (size_t)b * NC * NPIX + ch * 512;
    int r0 = tid >> 4;              // row base (0..31), rows r0+32i
    int k40 = tid & 15;             // float4 col within 64-px tile

    float4 pv[8];                   // prefetch registers (32 VGPR)

    auto LOAD = [&](int kk) {
#pragma unroll
        for (int i = 0; i < 8; ++i)
            pv[i] = *(const float4*)(Xb + (size_t)(r0 + 32 * i) * NPIX + kk * 64 + k40 * 4);
    };
    auto CONV = [&](int d) {
#pragma unroll
        for (int i = 0; i < 8; ++i) {
            float4 v = pv[i];
            rsum[i] += v.x + v.y + v.z + v.w;
            unsigned short h0, h1, h2, h3, l0, l1, l2, l3;
            splitbf(v.x, h0, l0); splitbf(v.y, h1, l1);
            splitbf(v.z, h2, l2); splitbf(v.w, h3, l3);
            int r = r0 + 32 * i;
            int e0 = (r * 64 + k40 * 4) ^ ((r & 7) << 3);
            uint2 hu, lu;
            hu.x = (unsigned)h0 | ((unsigned)h1 << 16);
            hu.y = (unsigned)h2 | ((unsigned)h3 << 16);
            lu.x = (unsigned)l0 | ((unsigned)l1 << 16);
            lu.y = (unsigned)l2 | ((unsigned)l3 << 16);
            *(uint2*)&Thi[d][e0] = hu;
            *(uint2*)&Tlo[d][e0] = lu;
        }
    };

    LOAD(0);
    CONV(0);

    for (int kk = 0; kk < 8; ++kk) {   // 8 K-tiles of 64 px
        int cur = kk & 1;
        if (kk < 7) LOAD(kk + 1);      // issue next-tile loads early
        __syncthreads();               // buf[cur] fully written
#pragma unroll
        for (int ks = 0; ks < 2; ++ks) {
            short8 bh[4], bl[4];
#pragma unroll
            for (int ni = 0; ni < 4; ++ni) {
                int row = wcol * 64 + ni * 16 + lrow;
                int e = (row * 64 + ks * 32 + lk8) ^ ((row & 7) << 3);
                bh[ni] = *(const short8*)&Thi[cur][e];
                bl[ni] = *(const short8*)&Tlo[cur][e];
            }
#pragma unroll
            for (int mi = 0; mi < 8; ++mi) {
                int row = wrow * 128 + mi * 16 + lrow;
                int e = (row * 64 + ks * 32 + lk8) ^ ((row & 7) << 3);
                short8 ah = *(const short8*)&Thi[cur][e];
                short8 al = *(const short8*)&Tlo[cur][e];
#pragma unroll
                for (int ni = 0; ni < 4; ++ni) {
                    acc[mi][ni] = __builtin_amdgcn_mfma_f32_16x16x32_bf16(ah, bh[ni], acc[mi][ni], 0, 0, 0);
                    acc[mi][ni] = __builtin_amdgcn_mfma_f32_16x16x32_bf16(ah, bl[ni], acc[mi][ni], 0, 0, 0);
                    acc[mi][ni] = __builtin_amdgcn_mfma_f32_16x16x32_bf16(al, bh[ni], acc[mi][ni], 0, 0, 0);
                }
            }
        }
        if (kk < 7) CONV(cur ^ 1);     // write next tile (other buffer)
    }

    float* pb = Pout + ((size_t)(b * 32 + ch)) * 65536;
    int lr4 = (lane >> 4) << 2;
    int lc = lane & 15;
#pragma unroll
    for (int mi = 0; mi < 8; ++mi)
#pragma unroll
        for (int ni = 0; ni < 4; ++ni)
#pragma unroll
            for (int j = 0; j < 4; ++j) {
                int gr = wrow * 128 + mi * 16 + lr4 + j;
                int gc = wcol * 64 + ni * 16 + lc;
                pb[gr * 256 + gc] = acc[mi][ni][j];
            }
#pragma unroll
    for (int i = 0; i < 8; ++i) {
        float rs = rsum[i];
        rs += __shfl_down(rs, 8, 16);
        rs += __shfl_down(rs, 4, 16);
        rs += __shfl_down(rs, 2, 16);
        rs += __shfl_down(rs, 1, 16);
        if ((tid & 15) == 0)
            atomicAdd(&S[b * 256 + r0 + 32 * i], rs);
    }
}

// ---------------- reduce 32 chunk-partials -> G (vectorized) ----------------
__global__ __launch_bounds__(256) void k_reduce(const float* __restrict__ Pin,
                                                float* __restrict__ G) {
    int bx = blockIdx.x;            // 512 = 8 b * 64 segs of 1024 floats
    int b = bx >> 6, seg = bx & 63;
    int t = threadIdx.x;
    size_t i0 = (size_t)seg * 1024 + (size_t)t * 4;
    const float* base = Pin + (size_t)b * 32 * 65536 + i0;
    f32x4 s = {0.f, 0.f, 0.f, 0.f};
#pragma unroll 4
    for (int chk = 0; chk < 32; ++chk)
        s += *(const f32x4*)(base + (size_t)chk * 65536);
    *(f32x4*)(G + (size_t)b * 65536 + i0) = s;
}

// ---------------- uw: u = Wq s, w = Wk s ----------------
__global__ void k_uw(const float* __restrict__ WqT, const float* __restrict__ WkT,
                     const float* __restrict__ S, float* __restrict__ U,
                     float* __restrict__ Wvec) {
    int b = blockIdx.x, d = threadIdx.x;
    __shared__ float sl[256];
    sl[d] = S[b * 256 + d];
    __syncthreads();
    float u = 0.f, w = 0.f;
    for (int c = 0; c < 256; ++c) {
        float sv = sl[c];
        u += WqT[c * 256 + d] * sv;
        w += WkT[c * 256 + d] * sv;
    }
    U[b * 256 + d] = u;
    Wvec[b * 256 + d] = w;
}

// ---------------- fused middle chain: per (b, 16-row D-tile) ----------------
// Pq = Wq_tile * G_b ; logits = Pq * WkT_head + rank1 ; softmax ; Mg = gamma*attn*Wv_head ; Tvec
__global__ __launch_bounds__(256) void k_mid(const float* __restrict__ Wq,
                                             const float* __restrict__ G,
                                             const float* __restrict__ WkT,
                                             const float* __restrict__ Wv,
                                             const float* __restrict__ bq,
                                             const float* __restrict__ bk,
                                             const float* __restrict__ bv,
                                             const float* __restrict__ U,
                                             const float* __restrict__ Wvec,
                                             const float* __restrict__ gamma,
                                             unsigned short* __restrict__ Mgb,
                                             float* __restrict__ Tvec) {
    int bx = blockIdx.x;            // 128 = 8 b * 16 dt
    int b = bx >> 4, dt = bx & 15;
    int Dbase = dt * 16;
    int h = dt >> 3;                // head
    int t = threadIdx.x;
    int rg = t >> 5;                // 0..7 row-group
    int cg = t & 31;                // 0..31 col-group
    int r0 = rg * 2, r1 = r0 + 1;

    __shared__ __align__(16) float smem[24576];
    float* WqL = smem;
    float* PqL = smem + 4096;
    float* BIG = smem + 8192;
    float* AttL = smem;

#pragma unroll
    for (int i = 0; i < 4; ++i) {
        int f = t + i * 256;        // 1024 float4
        int row = f >> 6, c4 = (f & 63) * 4;
        *(float4*)&WqL[row * 256 + c4] = *(const float4*)(Wq + (size_t)(Dbase + row) * 256 + c4);
    }

    // ---- Phase B: Pq_tile = Wq_tile x G_b, 4 panels of 64 G-rows ----
    f32x4 pqA0 = {0,0,0,0}, pqA1 = pqA0, pqB0 = pqA0, pqB1 = pqA0;
    const float* Gb = G + (size_t)b * 65536;
    for (int p = 0; p < 4; ++p) {
        __syncthreads();
#pragma unroll
        for (int i = 0; i < 16; ++i) {
            int f = t + i * 256;    // 4096 float4
            int row = f >> 6, c4 = (f & 63) * 4;
            *(float4*)&BIG[row * 256 + c4] = *(const float4*)(Gb + (size_t)(p * 64 + row) * 256 + c4);
        }
        __syncthreads();
#pragma unroll 2
        for (int c = 0; c < 64; ++c) {
            float wq0 = WqL[r0 * 256 + p * 64 + c];
            float wq1 = WqL[r1 * 256 + p * 64 + c];
            f32x4 ga = *(const f32x4*)&BIG[c * 256 + cg * 4];
            f32x4 gb = *(const f32x4*)&BIG[c * 256 + 128 + cg * 4];
            pqA0 += wq0 * ga; pqB0 += wq0 * gb;
            pqA1 += wq1 * ga; pqB1 += wq1 * gb;
        }
    }
    __syncthreads();
    *(f32x4*)&PqL[r0 * 256 + cg * 4]       = pqA0;
    *(f32x4*)&PqL[r0 * 256 + 128 + cg * 4] = pqB0;
    *(f32x4*)&PqL[r1 * 256 + cg * 4]       = pqA1;
    *(f32x4*)&PqL[r1 * 256 + 128 + cg * 4] = pqB1;
    __syncthreads();

    // ---- Phase C: logits[16][128] = Pq_tile x WkT[:, head] ----
    f32x4 l0 = {0,0,0,0}, l1 = l0;
    for (int q = 0; q < 2; ++q) {
        if (q) __syncthreads();
#pragma unroll
        for (int i = 0; i < 16; ++i) {
            int f = t + i * 256;    // 4096 float4
            int row = f >> 5, c4 = (f & 31) * 4;
            *(float4*)&BIG[row * 128 + c4] = *(const float4*)(WkT + (size_t)(q * 128 + row) * 256 + h * 128 + c4);
        }
        __syncthreads();
#pragma unroll 2
        for (int c = 0; c < 128; ++c) {
            float p0 = PqL[r0 * 256 + q * 128 + c];
            float p1 = PqL[r1 * 256 + q * 128 + c];
            f32x4 kv = *(const f32x4*)&BIG[c * 128 + cg * 4];
            l0 += p0 * kv;
            l1 += p1 * kv;
        }
    }

    // ---- Phase D: rank-1 terms + softmax over 32 lanes ----
    int D0 = Dbase + r0, D1 = Dbase + r1;
    float bq0 = bq[D0], bq1 = bq[D1];
    float u0 = U[b * 256 + D0], u1 = U[b * 256 + D1];
    float g0 = gamma[0];
    float m0 = -3.0e38f, m1 = -3.0e38f;
#pragma unroll
    for (int j = 0; j < 4; ++j) {
        int E = h * 128 + cg * 4 + j;
        float wv = Wvec[b * 256 + E];
        float bkE = bk[E];
        float t0 = l0[j] + bq0 * wv + bkE * u0 + 16384.f * bq0 * bkE;
        float t1 = l1[j] + bq1 * wv + bkE * u1 + 16384.f * bq1 * bkE;
        l0[j] = t0; l1[j] = t1;
        m0 = fmaxf(m0, t0); m1 = fmaxf(m1, t1);
    }
#pragma unroll
    for (int k = 1; k < 32; k <<= 1) {
        m0 = fmaxf(m0, __shfl_xor(m0, k, 32));
        m1 = fmaxf(m1, __shfl_xor(m1, k, 32));
    }
    float s0 = 0.f, s1 = 0.f;
#pragma unroll
    for (int j = 0; j < 4; ++j) {
        float e0 = __expf(l0[j] - m0);
        float e1 = __expf(l1[j] - m1);
        l0[j] = e0; l1[j] = e1;
        s0 += e0; s1 += e1;
    }
#pragma unroll
    for (int k = 1; k < 32; k <<= 1) {
        s0 += __shfl_xor(s0, k, 32);
        s1 += __shfl_xor(s1, k, 32);
    }
    float inv0 = 1.f / s0, inv1 = 1.f / s1;
    float tv0 = 0.f, tv1 = 0.f;
#pragma unroll
    for (int j = 0; j < 4; ++j) {
        float a0 = l0[j] * inv0;
        float a1 = l1[j] * inv1;
        l0[j] = a0; l1[j] = a1;
        float bvE = bv[h * 128 + cg * 4 + j];
        tv0 += a0 * bvE; tv1 += a1 * bvE;
    }
#pragma unroll
    for (int k = 1; k < 32; k <<= 1) {
        tv0 += __shfl_xor(tv0, k, 32);
        tv1 += __shfl_xor(tv1, k, 32);
    }
    __syncthreads();   // WqL dead; AttL aliases it
    *(f32x4*)&AttL[r0 * 128 + cg * 4] = l0;
    *(f32x4*)&AttL[r1 * 128 + cg * 4] = l1;
    if (cg == 0) {
        Tvec[b * 256 + D0] = g0 * tv0;
        Tvec[b * 256 + D1] = g0 * tv1;
    }

    // ---- Phase E: Mg = gamma * attn x Wv[head rows] ----
    for (int q2 = 0; q2 < 2; ++q2) {
        __syncthreads();
#pragma unroll
        for (int i = 0; i < 16; ++i) {
            int f = t + i * 256;
            int row = f >> 5, c4 = (f & 31) * 4;
            *(float4*)&BIG[row * 128 + c4] = *(const float4*)(Wv + (size_t)(h * 128 + row) * 256 + q2 * 128 + c4);
        }
        __syncthreads();
        f32x4 mg0 = {0,0,0,0}, mg1 = mg0;
#pragma unroll 2
        for (int e = 0; e < 128; ++e) {
            float a0 = AttL[r0 * 128 + e];
            float a1 = AttL[r1 * 128 + e];
            f32x4 wv = *(const f32x4*)&BIG[e * 128 + cg * 4];
            mg0 += a0 * wv;
            mg1 += a1 * wv;
        }
        uint2 w0, w1;
        w0.x = (unsigned)bf16bits(g0 * mg0[0]) | ((unsigned)bf16bits(g0 * mg0[1]) << 16);
        w0.y = (unsigned)bf16bits(g0 * mg0[2]) | ((unsigned)bf16bits(g0 * mg0[3]) << 16);
        w1.x = (unsigned)bf16bits(g0 * mg1[0]) | ((unsigned)bf16bits(g0 * mg1[1]) << 16);
        w1.y = (unsigned)bf16bits(g0 * mg1[2]) | ((unsigned)bf16bits(g0 * mg1[3]) << 16);
        *(uint2*)(Mgb + ((size_t)(b * 256 + D0)) * 256 + q2 * 128 + cg * 4) = w0;
        *(uint2*)(Mgb + ((size_t)(b * 256 + D1)) * 256 + q2 * 128 + cg * 4) = w1;
    }
}

// ---------------- apply: Y = Mg X + Tvec + X  (bf16 MFMA, fp32 residual from LDS) ----------------
__global__ __launch_bounds__(256, 2) void k_gemmC(const float* __restrict__ X,
                                                  const unsigned short* __restrict__ Mgb,
                                                  const float* __restrict__ Tvec,
                                                  float* __restrict__ Y) {
    int bx = blockIdx.x;            // 2048 = 8 b * 256 ntiles of 64 px
    int b = bx >> 8, nt = bx & 255;
    int n0 = nt * 64;
    int tid = threadIdx.x;
    int lane = tid & 63, w = tid >> 6;

    __shared__ float XL[256 * 64];

    const float* Xb = X + (size_t)b * NC * NPIX + n0;
#pragma unroll
    for (int i = 0; i < 16; ++i) {
        int flat = tid + i * 256;
        int c = flat >> 4;
        int n4 = (flat & 15) * 4;
        *(float4*)&XL[c * 64 + n4] = *(const float4*)(Xb + (size_t)c * NPIX + n4);
    }
    __syncthreads();

    int lr = lane & 15;
    int lk = (lane >> 4) * 8;

    f32x4 zero4 = {0.f, 0.f, 0.f, 0.f};
    f32x4 acc[4][4];
#pragma unroll
    for (int mi = 0; mi < 4; ++mi)
#pragma unroll
        for (int ni = 0; ni < 4; ++ni) acc[mi][ni] = zero4;

    const unsigned short* Mb = Mgb + (size_t)b * 65536;
    for (int ks = 0; ks < 8; ++ks) {
        int cb = ks * 32 + lk;
        short8 afr[4];
#pragma unroll
        for (int mi = 0; mi < 4; ++mi) {
            int r = w * 64 + mi * 16 + lr;
            afr[mi] = *(const short8*)(Mb + (size_t)r * 256 + cb);
        }
        short8 bfr[4];
#pragma unroll
        for (int ni = 0; ni < 4; ++ni) {
            int nn = ni * 16 + lr;
            short8 bb;
#pragma unroll
            for (int m = 0; m < 8; ++m) {
                float xv = XL[(cb + m) * 64 + nn];
                bb[m] = (short)bf16bits(xv);
            }
            bfr[ni] = bb;
        }
#pragma unroll
        for (int mi = 0; mi < 4; ++mi)
#pragma unroll
            for (int ni = 0; ni < 4; ++ni)
                acc[mi][ni] = __builtin_amdgcn_mfma_f32_16x16x32_bf16(afr[mi], bfr[ni], acc[mi][ni], 0, 0, 0);
    }
    int lr4 = (lane >> 4) * 4;
    int lc = lane & 15;
#pragma unroll
    for (int mi = 0; mi < 4; ++mi) {
#pragma unroll
        for (int j = 0; j < 4; ++j) {
            int r = w * 64 + mi * 16 + lr4 + j;
            float tv = Tvec[b * 256 + r];
            float* yr = Y + ((size_t)(b * 256 + r)) * NPIX + n0;
#pragma unroll
            for (int ni = 0; ni < 4; ++ni) {
                int nn = ni * 16 + lc;
                yr[nn] = acc[mi][ni][j] + tv + XL[r * 64 + nn];
            }
        }
    }
}

extern "C" void kernel_launch(void* const* d_in, const int* in_sizes, int n_in,
                              void* d_out, int out_size, void* d_ws, size_t ws_size,
                              hipStream_t stream) {
    (void)in_sizes; (void)n_in; (void)out_size; (void)ws_size;
    const float* X     = (const float*)d_in[0];
    const float* Wq    = (const float*)d_in[1];
    const float* bq    = (const float*)d_in[2];
    const float* Wk    = (const float*)d_in[3];
    const float* bk    = (const float*)d_in[4];
    const float* Wv    = (const float*)d_in[5];
    const float* bv    = (const float*)d_in[6];
    const float* gamma = (const float*)d_in[7];
    float* Y  = (float*)d_out;
    float* ws = (float*)d_ws;

    float* G    = ws + WS_G;
    float* S    = ws + WS_S;
    float* U    = ws + WS_U;
    float* Wvec = ws + WS_W;
    float* WkT  = ws + WS_WKT;
    float* WqT  = ws + WS_WQT;
    unsigned short* Mgb = (unsigned short*)(ws + WS_MGBF);
    float* Tvec = ws + WS_TV;
    float* Part = Y;   // Y reused: 256 partials x 65536 floats = 16.7M of Y's 33.5M;
                       // dead after k_reduce, rewritten by k_gemmC

    k_misc<<<dim3(256), dim3(256), 0, stream>>>(Wq, Wk, WqT, WkT, S);
    k_gemmA<<<dim3(256), dim3(512), 0, stream>>>(X, Part, S);
    k_reduce<<<dim3(512), dim3(256), 0, stream>>>(Part, G);
    k_uw<<<dim3(8), dim3(256), 0, stream>>>(WqT, WkT, S, U, Wvec);
    k_mid<<<dim3(128), dim3(256), 0, stream>>>(Wq, G, WkT, Wv, bq, bk, bv, U, Wvec, gamma, Mgb, Tvec);
    k_gemmC<<<dim3(2048), dim3(256), 0, stream>>>(X, Mgb, Tvec, Y);
}